// Round 5
// baseline (179.556 us; speedup 1.0000x reference)
//
#include <hip/hip_runtime.h>

constexpr int NB  = 2;     // batch
constexpr int NCI = 4;     // conv input channels
constexpr int NHH = 256;   // H
constexpr int NWW = 256;   // W
constexpr int NCT = 1024;  // conv output channels

// workspace layout (floats)
// G padded: [m][b][i][258][48], rows 0 and 257 are zeros (h_pad = h+1)
constexpr int G_OFF   = 0;
constexpr int G_ROWS  = 258;
constexpr int G_ISTR  = G_ROWS * 48;               // 12384
constexpr int G_MBSTR = NCI * G_ISTR;              // 49536
constexpr int G_SIZE  = 3 * NB * G_MBSTR;          // 297216
constexpr int SW1_OFF = G_OFF + G_SIZE;            // 3*16 column sums of W1
constexpr int Q_OFF   = SW1_OFF + 48;
constexpr int QKV_ONE = NB * 4 * NCT * 64;         // 524288
constexpr int K_OFF   = Q_OFF + QKV_ONE;           // k stored transposed [x][o]
constexpr int V_OFF   = K_OFF + QKV_ONE;

__device__ __forceinline__ float sigmoid_f(float v) {
  return __builtin_amdgcn_rcpf(1.0f + __expf(-v));
}

// K1: G[m][b][i][h+1][dx*16+r] = sum_w x_pad[b,i,h,w+dx-1] * W1_m[w,r]
// grid: 3*NB*NCI*(NHH/4) + 3, block 64  (unchanged)
__global__ __launch_bounds__(64) void k1_G(
    const float* __restrict__ x,
    const float* __restrict__ qW1, const float* __restrict__ kW1,
    const float* __restrict__ vW1, float* __restrict__ ws) {
  const int tid = threadIdx.x;
  const int NBLK = 3 * NB * NCI * (NHH / 4);
  int bid = blockIdx.x;
  if (bid >= NBLK) {  // column sums of W1 (for conv_b term)
    int m = bid - NBLK;
    if (tid < 16) {
      const float* W1 = (m == 0) ? qW1 : (m == 1) ? kW1 : vW1;
      float s = 0.f;
      for (int w = 0; w < 256; ++w) s += W1[w * 16 + tid];
      ws[SW1_OFF + m * 16 + tid] = s;
    }
    return;
  }
  const int m  = bid / (NB * NCI * (NHH / 4));
  int rem      = bid % (NB * NCI * (NHH / 4));
  const int b  = rem / (NCI * (NHH / 4));
  rem          = rem % (NCI * (NHH / 4));
  const int i  = rem / (NHH / 4);
  const int h0 = (rem % (NHH / 4)) * 4;

  const float* W1 = (m == 0) ? qW1 : (m == 1) ? kW1 : vW1;

  __shared__ float W1l[16 * 260];
  __shared__ float xlb[4][260];

  for (int idx4 = tid; idx4 < 1024; idx4 += 64) {
    const float4 t = ((const float4*)W1)[idx4];
    const int w = idx4 >> 2, r0 = (idx4 & 3) * 4;
    W1l[(r0 + 0) * 260 + w] = t.x;
    W1l[(r0 + 1) * 260 + w] = t.y;
    W1l[(r0 + 2) * 260 + w] = t.z;
    W1l[(r0 + 3) * 260 + w] = t.w;
  }
  const float* xbase = x + ((size_t)(b * NCI + i) * NHH + h0) * NWW;
  for (int idx = tid; idx < 4 * 256; idx += 64) {
    const int rr = idx >> 8, w = idx & 255;
    xlb[rr][1 + w] = xbase[rr * NWW + w];
  }
  if (tid < 4) {
    xlb[tid][0] = 0.f; xlb[tid][257] = 0.f; xlb[tid][258] = 0.f; xlb[tid][259] = 0.f;
  }
  __syncthreads();

  const int wc = tid >> 4, r = tid & 15;
  const int w0 = wc * 64;
  float* Gw = ws + G_OFF + (size_t)((m * NB + b) * NCI + i) * G_ISTR;

  // zero the pad rows (padded rows 0 and 257)
  if (h0 == 0   && tid < 48) Gw[tid] = 0.f;
  if (h0 == 252 && tid < 48) Gw[257 * 48 + tid] = 0.f;

  #pragma unroll
  for (int rr = 0; rr < 4; ++rr) {
    const float* xl = xlb[rr];
    float a0 = 0.f, a1 = 0.f, a2 = 0.f;
    float4 cur = *(const float4*)&xl[w0];
    #pragma unroll 4
    for (int w = w0; w < w0 + 64; w += 4) {
      const float4 nxt = *(const float4*)&xl[w + 4];
      const float4 w1  = *(const float4*)&W1l[r * 260 + w];
      a0 += w1.x * cur.x + w1.y * cur.y + w1.z * cur.z + w1.w * cur.w;
      a1 += w1.x * cur.y + w1.y * cur.z + w1.z * cur.w + w1.w * nxt.x;
      a2 += w1.x * cur.z + w1.y * cur.w + w1.z * nxt.x + w1.w * nxt.y;
      cur = nxt;
    }
    a0 += __shfl_xor(a0, 16, 64); a0 += __shfl_xor(a0, 32, 64);
    a1 += __shfl_xor(a1, 16, 64); a1 += __shfl_xor(a1, 32, 64);
    a2 += __shfl_xor(a2, 16, 64); a2 += __shfl_xor(a2, 32, 64);
    if (wc == 0) {
      float* g = Gw + (size_t)(h0 + rr + 1) * 48;   // +1 pad row
      g[r] = a0; g[16 + r] = a1; g[32 + r] = a2;
    }
  }
}

// K2: layer1 (conv x W1, K=36) + layer2 (W2 in SGPRs), h-tile = 16, 4 blocks/CU.
// grid 768 = NB*3*128 (8 o per block), block 512 = 8 waves.
// Each wave owns a uniform half of the 8 o's (phase 1) and a uniform s-quad (phase 2).
// LDS: Gl[4][18][48] + y1l[16 hl][8 o x17 + r]  = 22.5 KB.
__global__ __launch_bounds__(512, 8) void k2_mlp(
    const float* __restrict__ conv_w, const float* __restrict__ conv_b,
    const float* __restrict__ qb1, const float* __restrict__ qW2, const float* __restrict__ qb2,
    const float* __restrict__ kb1, const float* __restrict__ kW2, const float* __restrict__ kb2,
    const float* __restrict__ vb1, const float* __restrict__ vW2, const float* __restrict__ vb2,
    float* __restrict__ ws) {
  const int tid = threadIdx.x;
  const int bid = blockIdx.x;
  const int og = bid & 127;
  const int m  = (bid >> 7) % 3;
  const int b  = bid / 384;
  const int o0 = og * 8;

  const int wv   = tid >> 6;                    // wave 0..7
  const int lane = tid & 63;
  const int r    = lane & 15;
  const int lq   = lane >> 4;                   // 0..3

  // phase-1 mapping: (half, hl, r); half wave-uniform
  const int half = __builtin_amdgcn_readfirstlane(wv >> 2);   // 0..1
  const int hl   = (wv & 3) * 4 + lq;                          // 0..15
  // phase-2 mapping: (o_loc, r) x sq; sq wave-uniform
  const int sq    = __builtin_amdgcn_readfirstlane(wv & 3);    // 0..3
  const int o_loc = half * 4 + lq;                             // 0..7

  const float* b1 = (m == 0) ? qb1 : (m == 1) ? kb1 : vb1;
  const float* W2 = (m == 0) ? qW2 : (m == 1) ? kW2 : vW2;
  const float* b2 = (m == 0) ? qb2 : (m == 1) ? kb2 : vb2;

  __shared__ float LDS[5632];
  float* Gl  = LDS;            // [i][18*48=864]
  float* y1l = LDS + 3456;     // [hl][o*17 + r], hl-stride 136

  const float* Gbase = ws + G_OFF + (size_t)(m * NB + b) * G_MBSTR;
  const float sw1r = ws[SW1_OFF + m * 16 + r];
  const float b1r  = b1[r];
  const float* cw_base = conv_w + (size_t)(o0 + half * 4) * 36;  // uniform -> s_load
  const float* W2u = W2 + sq * 4;                                // uniform -> s_load
  float cb[4];
  #pragma unroll
  for (int j = 0; j < 4; ++j) cb[j] = conv_b[o0 + half * 4 + j];

  // staging mapping: thread-halves each stage 2 of the 4 i-slabs
  const int s_i0 = (tid >> 8) * 2;
  const int s_t  = tid & 255;

  float acc2[4] = {0.f, 0.f, 0.f, 0.f};

  for (int t = 0; t < 16; ++t) {
    const int h0 = t * 16;

    // stage G slab: padded rows h0..h0+17 per i (18*48 = 864 floats = 216 float4)
    if (s_t < 216) {
      #pragma unroll
      for (int di = 0; di < 2; ++di) {
        const int i = s_i0 + di;
        const float4 vv = *(const float4*)&Gbase[(size_t)i * G_ISTR + h0 * 48 + s_t * 4];
        *(float4*)&Gl[i * 864 + s_t * 4] = vv;
      }
    }
    __syncthreads();

    // phase 1: 4 o's at column (h = h0 + hl, r); g[9] batch per i
    {
      float acc[4];
      #pragma unroll
      for (int j = 0; j < 4; ++j) acc[j] = cb[j] * sw1r + b1r;
      const float* gl = Gl + hl * 48 + r;
      #pragma unroll
      for (int i = 0; i < 4; ++i) {
        float g[9];
        #pragma unroll
        for (int dy = 0; dy < 3; ++dy)
          #pragma unroll
          for (int dx = 0; dx < 3; ++dx)
            g[dy * 3 + dx] = gl[i * 864 + dy * 48 + dx * 16];
        #pragma unroll
        for (int j = 0; j < 4; ++j) {
          const float* cwp = cw_base + j * 36 + i * 9;
          #pragma unroll
          for (int q = 0; q < 9; ++q) acc[j] += cwp[q] * g[q];
        }
      }
      #pragma unroll
      for (int j = 0; j < 4; ++j)
        y1l[hl * 136 + (half * 4 + j) * 17 + r] = sigmoid_f(acc[j]);
    }
    __syncthreads();

    // phase 2: contract this tile's 16 h; y prefetched in two static batches of 8
    {
      const float* yb = y1l + o_loc * 17 + r;
      #pragma unroll
      for (int bq = 0; bq < 2; ++bq) {
        float yv[8];
        #pragma unroll
        for (int u = 0; u < 8; ++u) yv[u] = yb[(bq * 8 + u) * 136];
        #pragma unroll
        for (int u = 0; u < 8; ++u) {
          const int hh = bq * 8 + u;
          const float4 w2v = *(const float4*)&W2u[(h0 + hh) * 16];  // s_load_dwordx4
          acc2[0] += yv[u] * w2v.x; acc2[1] += yv[u] * w2v.y;
          acc2[2] += yv[u] * w2v.z; acc2[3] += yv[u] * w2v.w;
        }
      }
    }
    // no extra barrier: next staging writes Gl (last read before sync2);
    // next y1l writes are separated from these reads by next tile's sync1.
  }

  // epilogue: y2 -> LDS (Gl region, no overlap with y1l) -> coalesced stores
  #pragma unroll
  for (int j = 0; j < 4; ++j) {
    const int s = sq * 4 + j;
    const float y2 = sigmoid_f(acc2[j] + b2[s]);
    const int n   = (s & 1) * 2 + (r & 1);
    const int xsp = (s >> 1) * 8 + (r >> 1);
    LDS[o_loc * 256 + n * 64 + xsp] = y2;   // y2l[o_loc][n][xsp]
  }
  __syncthreads();

  if (m != 1) {  // q, v: [bn][o][xsp], fully coalesced float4 runs
    float* dst = ws + ((m == 0) ? Q_OFF : V_OFF);
    const int run = tid >> 4, pos = (tid & 15) * 4;
    const int n = run >> 3, o_l = run & 7;
    const float4 v4 = *(const float4*)&LDS[o_l * 256 + n * 64 + pos];
    *(float4*)&dst[((size_t)(b * 4 + n) * 1024 + o0 + o_l) * 64 + pos] = v4;
  } else {       // k: [bn][xsp][o], float4 chunks of 8-o run
    float* dst = ws + K_OFF;
    const int chunk = tid >> 1, halfc = tid & 1;
    const int n = chunk >> 6, xsp = chunk & 63;
    float4 v4;
    v4.x = LDS[(halfc * 4 + 0) * 256 + n * 64 + xsp];
    v4.y = LDS[(halfc * 4 + 1) * 256 + n * 64 + xsp];
    v4.z = LDS[(halfc * 4 + 2) * 256 + n * 64 + xsp];
    v4.w = LDS[(halfc * 4 + 3) * 256 + n * 64 + xsp];
    *(float4*)&dst[((size_t)(b * 4 + n) * 64 + xsp) * 1024 + o0 + halfc * 4] = v4;
  }
}

// K3: per (b,n): scores = q k^T * temp over 64-dim, softmax over e, @ v.
// grid 1024 = 8 bn x 128 row-groups (8 rows), block 256.  (unchanged)
__global__ __launch_bounds__(256) void k3_attn(
    const float* __restrict__ ws, const float* __restrict__ temp,
    float* __restrict__ out) {
  const int tid = threadIdx.x;
  const int bn = blockIdx.x >> 7;
  const int c0 = (blockIdx.x & 127) * 8;
  const float* q  = ws + Q_OFF + (size_t)bn * NCT * 64;
  const float* kT = ws + K_OFF + (size_t)bn * 64 * NCT;
  const float* v  = ws + V_OFF + (size_t)bn * NCT * 64;
  const float tscale = temp[bn & 3];

  __shared__ float S[8 * 1024];
  __shared__ float ql[64 * 8];
  __shared__ float lrow[8];

  for (int j = tid; j < 8 * 64; j += 256) {
    const int c = j >> 6, d = j & 63;
    ql[d * 8 + c] = q[(size_t)(c0 + c) * 64 + d];
  }
  __syncthreads();

  {
    float acc[32];
    #pragma unroll
    for (int j = 0; j < 32; ++j) acc[j] = 0.f;
    for (int d = 0; d < 64; ++d) {
      const float* kr = kT + (size_t)d * NCT;
      const float kv0 = kr[tid];
      const float kv1 = kr[tid + 256];
      const float kv2 = kr[tid + 512];
      const float kv3 = kr[tid + 768];
      #pragma unroll
      for (int c4 = 0; c4 < 2; ++c4) {
        const float4 qv = *(const float4*)&ql[d * 8 + c4 * 4];
        const float qa[4] = {qv.x, qv.y, qv.z, qv.w};
        #pragma unroll
        for (int jj = 0; jj < 4; ++jj) {
          const int cc = c4 * 4 + jj;
          acc[cc * 4 + 0] += qa[jj] * kv0;
          acc[cc * 4 + 1] += qa[jj] * kv1;
          acc[cc * 4 + 2] += qa[jj] * kv2;
          acc[cc * 4 + 3] += qa[jj] * kv3;
        }
      }
    }
    #pragma unroll
    for (int cc = 0; cc < 8; ++cc) {
      S[cc * 1024 + tid      ] = acc[cc * 4 + 0] * tscale;
      S[cc * 1024 + tid + 256] = acc[cc * 4 + 1] * tscale;
      S[cc * 1024 + tid + 512] = acc[cc * 4 + 2] * tscale;
      S[cc * 1024 + tid + 768] = acc[cc * 4 + 3] * tscale;
    }
  }
  __syncthreads();

  {
    const int c = tid >> 5, l = tid & 31;
    float* row = &S[c * 1024];
    float mx = -1e30f;
    for (int j = l; j < 1024; j += 32) mx = fmaxf(mx, row[j]);
    #pragma unroll
    for (int msk = 1; msk < 32; msk <<= 1) mx = fmaxf(mx, __shfl_xor(mx, msk, 64));
    float sum = 0.f;
    for (int j = l; j < 1024; j += 32) {
      const float p = __expf(row[j] - mx);
      row[j] = p;
      sum += p;
    }
    #pragma unroll
    for (int msk = 1; msk < 32; msk <<= 1) sum += __shfl_xor(sum, msk, 64);
    if (l == 0) lrow[c] = sum;
  }
  __syncthreads();

  {
    const int xx = tid & 63, cq = tid >> 6;
    float a0 = 0.f, a1 = 0.f;
    for (int e = 0; e < 1024; e += 4) {
      const float v0 = v[(size_t)(e + 0) * 64 + xx];
      const float v1 = v[(size_t)(e + 1) * 64 + xx];
      const float v2 = v[(size_t)(e + 2) * 64 + xx];
      const float v3 = v[(size_t)(e + 3) * 64 + xx];
      const float4 p0 = *(const float4*)&S[(cq * 2 + 0) * 1024 + e];
      const float4 p1 = *(const float4*)&S[(cq * 2 + 1) * 1024 + e];
      a0 += p0.x * v0 + p0.y * v1 + p0.z * v2 + p0.w * v3;
      a1 += p1.x * v0 + p1.y * v1 + p1.z * v2 + p1.w * v3;
    }
    #pragma unroll
    for (int jr = 0; jr < 2; ++jr) {
      const int c = c0 + cq * 2 + jr;
      const float val = ((jr == 0) ? a0 : a1) / lrow[cq * 2 + jr];
      out[((size_t)bn * 256 + (c >> 2)) * 256 + 64 * (c & 3) + xx] = val;
    }
  }
}

extern "C" void kernel_launch(void* const* d_in, const int* in_sizes, int n_in,
                              void* d_out, int out_size, void* d_ws, size_t ws_size,
                              hipStream_t stream) {
  (void)in_sizes; (void)n_in; (void)out_size; (void)ws_size;
  const float* x      = (const float*)d_in[0];
  const float* conv_w = (const float*)d_in[1];
  const float* conv_b = (const float*)d_in[2];
  const float* qW1 = (const float*)d_in[3];
  const float* qb1 = (const float*)d_in[4];
  const float* qW2 = (const float*)d_in[5];
  const float* qb2 = (const float*)d_in[6];
  const float* kW1 = (const float*)d_in[7];
  const float* kb1 = (const float*)d_in[8];
  const float* kW2 = (const float*)d_in[9];
  const float* kb2 = (const float*)d_in[10];
  const float* vW1 = (const float*)d_in[11];
  const float* vb1 = (const float*)d_in[12];
  const float* vW2 = (const float*)d_in[13];
  const float* vb2 = (const float*)d_in[14];
  const float* temp = (const float*)d_in[15];
  float* ws  = (float*)d_ws;
  float* out = (float*)d_out;

  k1_G<<<dim3(3 * NB * NCI * (NHH / 4) + 3), dim3(64), 0, stream>>>(x, qW1, kW1, vW1, ws);
  k2_mlp<<<dim3(768), dim3(512), 0, stream>>>(conv_w, conv_b,
      qb1, qW2, qb2, kb1, kW2, kb2, vb1, vW2, vb2, ws);
  k3_attn<<<dim3(1024), dim3(256), 0, stream>>>(ws, temp, out);
}

// Round 6
// 94.335 us; speedup vs baseline: 1.9034x; 1.9034x over previous
//
#include <hip/hip_runtime.h>
#include <cstdint>

constexpr int NB  = 2;     // batch
constexpr int NCI = 4;     // conv input channels
constexpr int NHH = 256;   // H
constexpr int NWW = 256;   // W
constexpr int NCT = 1024;  // conv output channels

// ---------------- workspace layout ----------------
// float region (indices into (float*)d_ws):
constexpr size_t QF   = 0;          // q  [bn][o][xsp]   fp32
constexpr size_t KF   = 524288;     // kT [bn][xsp][o]   fp32
constexpr size_t VF   = 1048576;    // v  [bn][o][xsp]   fp32
constexpr size_t SW1F = 1572864;    // 3*16 column sums of W1 (fp32)
// uint16 (bf16) region starts at float index 1572912 (byte 6291648, 16B aligned):
constexpr size_t U16_BASE_F = 1572912;
constexpr size_t GP_U  = 0;         // G'bf [m][b][i][dx][r][258]  (h-contig, rows 0/257 zero)
constexpr size_t CW_U  = 297216;    // CW_bf [o][40]  (k = i*9+dy*3+dx, 36..39 zero)
constexpr size_t W2T_U = 338176;    // W2T_bf [m][s][h]  16x256 per m

typedef __attribute__((ext_vector_type(8))) short bf16x8;
typedef __attribute__((ext_vector_type(4))) float f32x4;

__device__ __forceinline__ uint16_t f2bf(float x) {
  uint32_t u = __float_as_uint(x);
  return (uint16_t)((u + 0x7FFFu + ((u >> 16) & 1u)) >> 16);   // RNE
}
__device__ __forceinline__ float sigmoid_f(float v) {
  return __builtin_amdgcn_rcpf(1.0f + __expf(-v));
}

// K1: G'bf[m][b][i][dx][r][1+h] = bf16( sum_w x_pad[b,i,h,w+dx-1] * W1_m[w,r] )
// plus sw1 sums, plus CW_bf / W2T_bf prep blocks.
// grid: 1536 (G) + 3 (sw1) + 64 (CW) + 3 (W2T) = 1606, block 64
__global__ __launch_bounds__(64) void k1_G(
    const float* __restrict__ x,
    const float* __restrict__ qW1, const float* __restrict__ kW1,
    const float* __restrict__ vW1,
    const float* __restrict__ conv_w,
    const float* __restrict__ qW2, const float* __restrict__ kW2,
    const float* __restrict__ vW2,
    float* __restrict__ wsf, uint16_t* __restrict__ wsu) {
  const int tid = threadIdx.x;
  const int NBLK = 3 * NB * NCI * (NHH / 4);   // 1536
  int bid = blockIdx.x;

  if (bid >= NBLK + 3 + 64) {                  // W2T_bf prep (3 blocks)
    const int m = bid - (NBLK + 3 + 64);
    const float* W2 = (m == 0) ? qW2 : (m == 1) ? kW2 : vW2;
    for (int u = 0; u < 64; ++u) {
      const int idx = tid * 64 + u;            // 4096 = 16 s x 256 h
      const int s = idx >> 8, h = idx & 255;
      wsu[W2T_U + (size_t)m * 4096 + s * 256 + h] = f2bf(W2[h * 16 + s]);
    }
    return;
  }
  if (bid >= NBLK + 3) {                       // CW_bf prep (64 blocks x 16 o)
    const int p = bid - (NBLK + 3);
    const int o = p * 16 + (tid >> 2);
    const int ks = (tid & 3) * 10;
    for (int u = 0; u < 10; ++u) {
      const int k = ks + u;
      wsu[CW_U + (size_t)o * 40 + k] = (k < 36) ? f2bf(conv_w[o * 36 + k]) : (uint16_t)0;
    }
    return;
  }
  if (bid >= NBLK) {                           // sw1 column sums
    int m = bid - NBLK;
    if (tid < 16) {
      const float* W1 = (m == 0) ? qW1 : (m == 1) ? kW1 : vW1;
      float s = 0.f;
      for (int w = 0; w < 256; ++w) s += W1[w * 16 + tid];
      wsf[SW1F + m * 16 + tid] = s;
    }
    return;
  }

  const int m  = bid / (NB * NCI * (NHH / 4));
  int rem      = bid % (NB * NCI * (NHH / 4));
  const int b  = rem / (NCI * (NHH / 4));
  rem          = rem % (NCI * (NHH / 4));
  const int i  = rem / (NHH / 4);
  const int h0 = (rem % (NHH / 4)) * 4;
  const int mb = m * NB + b;

  const float* W1 = (m == 0) ? qW1 : (m == 1) ? kW1 : vW1;

  __shared__ float W1l[16 * 260];
  __shared__ float xlb[4][260];

  for (int idx4 = tid; idx4 < 1024; idx4 += 64) {
    const float4 t = ((const float4*)W1)[idx4];
    const int w = idx4 >> 2, r0 = (idx4 & 3) * 4;
    W1l[(r0 + 0) * 260 + w] = t.x;
    W1l[(r0 + 1) * 260 + w] = t.y;
    W1l[(r0 + 2) * 260 + w] = t.z;
    W1l[(r0 + 3) * 260 + w] = t.w;
  }
  const float* xbase = x + ((size_t)(b * NCI + i) * NHH + h0) * NWW;
  for (int idx = tid; idx < 4 * 256; idx += 64) {
    const int rr = idx >> 8, w = idx & 255;
    xlb[rr][1 + w] = xbase[rr * NWW + w];
  }
  if (tid < 4) {
    xlb[tid][0] = 0.f; xlb[tid][257] = 0.f; xlb[tid][258] = 0.f; xlb[tid][259] = 0.f;
  }
  __syncthreads();

  // pad rows hp=0 and hp=257 (zeros)
  if (h0 == 0 && tid < 48) {
    const int dxp = tid >> 4, rp = tid & 15;
    wsu[GP_U + ((size_t)((mb * 4 + i) * 3 + dxp) * 16 + rp) * 258 + 0] = 0;
  }
  if (h0 == 252 && tid < 48) {
    const int dxp = tid >> 4, rp = tid & 15;
    wsu[GP_U + ((size_t)((mb * 4 + i) * 3 + dxp) * 16 + rp) * 258 + 257] = 0;
  }

  const int wc = tid >> 4, r = tid & 15;
  const int w0 = wc * 64;
  const size_t gb0 = GP_U + ((size_t)((mb * 4 + i) * 3 + 0) * 16 + r) * 258;   // dx stride 16*258

  #pragma unroll
  for (int rr = 0; rr < 4; ++rr) {
    const float* xl = xlb[rr];
    float a0 = 0.f, a1 = 0.f, a2 = 0.f;
    float4 cur = *(const float4*)&xl[w0];
    #pragma unroll 4
    for (int w = w0; w < w0 + 64; w += 4) {
      const float4 nxt = *(const float4*)&xl[w + 4];
      const float4 w1  = *(const float4*)&W1l[r * 260 + w];
      a0 += w1.x * cur.x + w1.y * cur.y + w1.z * cur.z + w1.w * cur.w;
      a1 += w1.x * cur.y + w1.y * cur.z + w1.z * cur.w + w1.w * nxt.x;
      a2 += w1.x * cur.z + w1.y * cur.w + w1.z * nxt.x + w1.w * nxt.y;
      cur = nxt;
    }
    a0 += __shfl_xor(a0, 16, 64); a0 += __shfl_xor(a0, 32, 64);
    a1 += __shfl_xor(a1, 16, 64); a1 += __shfl_xor(a1, 32, 64);
    a2 += __shfl_xor(a2, 16, 64); a2 += __shfl_xor(a2, 32, 64);
    if (wc == 0) {
      const int hp = 1 + h0 + rr;
      wsu[gb0 + hp]            = f2bf(a0);   // dx = 0
      wsu[gb0 + 4128 + hp]     = f2bf(a1);   // dx = 1  (16*258)
      wsu[gb0 + 8256 + hp]     = f2bf(a2);   // dx = 2
    }
  }
}

// K2 (MFMA): per block = (m, b, 64 o, r). GS in LDS once; per wave (16 o):
// 4 chunks of 64 h: GEMM1 (8 mfma) -> sigmoid -> y1 bf16 (wave-private LDS)
// -> GEMM2 (2 mfma, acc chained). One barrier total.
// grid 1536 = 6 mb x 16 og x 16 r, block 256 = 4 waves.
__global__ __launch_bounds__(256, 4) void k2_mfma(
    const uint16_t* __restrict__ gp, const uint16_t* __restrict__ cwbf,
    const uint16_t* __restrict__ w2t,
    const float* __restrict__ conv_b,
    const float* __restrict__ qb1, const float* __restrict__ kb1, const float* __restrict__ vb1,
    const float* __restrict__ qb2, const float* __restrict__ kb2, const float* __restrict__ vb2,
    float* __restrict__ wsf) {
  const int tid = threadIdx.x;
  const int bid = blockIdx.x;
  const int r  = bid & 15;
  const int og = (bid >> 4) & 15;
  const int mb = bid >> 8;            // 0..5
  const int m  = mb >> 1, b = mb & 1;

  const int wv  = tid >> 6;
  const int l   = tid & 63;
  const int l15 = l & 15;
  const int lg  = l >> 4;

  __shared__ uint16_t GS[256 * 40];     // [h][k], k-contig, rows 80 B
  __shared__ uint16_t y1l[4][16 * 72];  // per-wave [o16][h64+8pad] bf16

  // ---- build GS (all 256 threads, h = tid) ----
  {
    const int h = tid;
    uint16_t* gsrow = &GS[h * 40];
    #pragma unroll
    for (int i = 0; i < 4; ++i) {
      #pragma unroll
      for (int dx = 0; dx < 3; ++dx) {
        const uint16_t* g = gp + ((size_t)((mb * 4 + i) * 3 + dx) * 16 + r) * 258 + h;
        gsrow[i * 9 + 0 * 3 + dx] = g[0];   // dy = 0
        gsrow[i * 9 + 1 * 3 + dx] = g[1];   // dy = 1
        gsrow[i * 9 + 2 * 3 + dx] = g[2];   // dy = 2
      }
    }
    gsrow[36] = 0; gsrow[37] = 0; gsrow[38] = 0; gsrow[39] = 0;
  }
  __syncthreads();

  const float* b1 = (m == 0) ? qb1 : (m == 1) ? kb1 : vb1;
  const float* b2 = (m == 0) ? qb2 : (m == 1) ? kb2 : vb2;

  const int o_blk = og * 64 + wv * 16;

  // CW B-frags (B[k][col=o] read from CW_bf[o][k..k+8])
  const uint16_t* cwrow = cwbf + (size_t)(o_blk + l15) * 40;
  bf16x8 cw0 = *(const bf16x8*)(cwrow + lg * 8);
  bf16x8 cw1 = {0,0,0,0,0,0,0,0};
  if (lg == 0) cw1 = *(const bf16x8*)(cwrow + 32);

  // W2T B-frags (B[k=h][col=s] read from W2T[s][h..h+8]), all 8 K-chunks
  const uint16_t* w2row = w2t + (size_t)m * 4096 + (size_t)l15 * 256 + lg * 8;
  bf16x8 w2f0 = *(const bf16x8*)(w2row + 0 * 32);
  bf16x8 w2f1 = *(const bf16x8*)(w2row + 1 * 32);
  bf16x8 w2f2 = *(const bf16x8*)(w2row + 2 * 32);
  bf16x8 w2f3 = *(const bf16x8*)(w2row + 3 * 32);
  bf16x8 w2f4 = *(const bf16x8*)(w2row + 4 * 32);
  bf16x8 w2f5 = *(const bf16x8*)(w2row + 5 * 32);
  bf16x8 w2f6 = *(const bf16x8*)(w2row + 6 * 32);
  bf16x8 w2f7 = *(const bf16x8*)(w2row + 7 * 32);

  const float sw1r = wsf[SW1F + m * 16 + r];
  const float b1r  = b1[r];
  const float cbv  = conv_b[o_blk + l15];        // o is the GEMM1 column = l15
  const float bias1 = cbv * sw1r + b1r;
  const float b2v  = b2[l15];                    // s = l15 in GEMM2

  uint16_t* yw = &y1l[wv][0];
  f32x4 acc2 = {0.f, 0.f, 0.f, 0.f};

  #pragma unroll
  for (int cc = 0; cc < 4; ++cc) {               // 64-h chunk
    // GEMM1: D1[h-local][o-local], 4 c'-tiles x K=64(40)
    #pragma unroll
    for (int ct = 0; ct < 4; ++ct) {
      const uint16_t* arow = &GS[(cc * 64 + ct * 16 + l15) * 40];
      bf16x8 a0 = *(const bf16x8*)(arow + lg * 8);
      bf16x8 a1 = {0,0,0,0,0,0,0,0};
      if (lg == 0) a1 = *(const bf16x8*)(arow + 32);
      f32x4 d = {0.f, 0.f, 0.f, 0.f};
      d = __builtin_amdgcn_mfma_f32_16x16x32_bf16(a0, cw0, d, 0, 0, 0);
      d = __builtin_amdgcn_mfma_f32_16x16x32_bf16(a1, cw1, d, 0, 0, 0);
      // sigmoid + pack to y1l[o=l15][h = ct*16 + lg*4 + p]
      const float y0 = sigmoid_f(d[0] + bias1);
      const float y1 = sigmoid_f(d[1] + bias1);
      const float y2 = sigmoid_f(d[2] + bias1);
      const float y3 = sigmoid_f(d[3] + bias1);
      uint32_t* yd = (uint32_t*)&yw[l15 * 72 + ct * 16 + lg * 4];
      yd[0] = (uint32_t)f2bf(y0) | ((uint32_t)f2bf(y1) << 16);
      yd[1] = (uint32_t)f2bf(y2) | ((uint32_t)f2bf(y3) << 16);
    }
    // GEMM2: D2[o][s] += y1[o][h] * W2[h][s] over this chunk's 64 h
    {
      const uint16_t* yrow = &yw[l15 * 72 + lg * 8];
      bf16x8 ya0 = *(const bf16x8*)(yrow + 0);
      bf16x8 ya1 = *(const bf16x8*)(yrow + 32);
      if (cc == 0) {
        acc2 = __builtin_amdgcn_mfma_f32_16x16x32_bf16(ya0, w2f0, acc2, 0, 0, 0);
        acc2 = __builtin_amdgcn_mfma_f32_16x16x32_bf16(ya1, w2f1, acc2, 0, 0, 0);
      } else if (cc == 1) {
        acc2 = __builtin_amdgcn_mfma_f32_16x16x32_bf16(ya0, w2f2, acc2, 0, 0, 0);
        acc2 = __builtin_amdgcn_mfma_f32_16x16x32_bf16(ya1, w2f3, acc2, 0, 0, 0);
      } else if (cc == 2) {
        acc2 = __builtin_amdgcn_mfma_f32_16x16x32_bf16(ya0, w2f4, acc2, 0, 0, 0);
        acc2 = __builtin_amdgcn_mfma_f32_16x16x32_bf16(ya1, w2f5, acc2, 0, 0, 0);
      } else {
        acc2 = __builtin_amdgcn_mfma_f32_16x16x32_bf16(ya0, w2f6, acc2, 0, 0, 0);
        acc2 = __builtin_amdgcn_mfma_f32_16x16x32_bf16(ya1, w2f7, acc2, 0, 0, 0);
      }
    }
  }

  // epilogue: y2 = sigmoid(acc2 + b2), scatter to q/k/v
  const int s   = l15;
  const int n   = (s & 1) * 2 + (r & 1);
  const int xsp = (s >> 1) * 8 + (r >> 1);
  const int bn  = b * 4 + n;
  float* qv = wsf + ((m == 0) ? QF : VF);
  float* kT = wsf + KF;
  #pragma unroll
  for (int p = 0; p < 4; ++p) {
    const int o = o_blk + lg * 4 + p;             // D2 row
    const float y2 = sigmoid_f(acc2[p] + b2v);
    if (m == 1) kT[((size_t)bn * 64 + xsp) * 1024 + o] = y2;
    else        qv[((size_t)bn * 1024 + o) * 64 + xsp] = y2;
  }
}

// K3: per (b,n): scores = q k^T * temp over 64-dim, softmax over e, @ v.
// grid 1024 = 8 bn x 128 row-groups (8 rows), block 256.  (unchanged)
__global__ __launch_bounds__(256) void k3_attn(
    const float* __restrict__ ws, const float* __restrict__ temp,
    float* __restrict__ out) {
  const int tid = threadIdx.x;
  const int bn = blockIdx.x >> 7;
  const int c0 = (blockIdx.x & 127) * 8;
  const float* q  = ws + QF + (size_t)bn * NCT * 64;
  const float* kT = ws + KF + (size_t)bn * 64 * NCT;
  const float* v  = ws + VF + (size_t)bn * NCT * 64;
  const float tscale = temp[bn & 3];

  __shared__ float S[8 * 1024];
  __shared__ float ql[64 * 8];
  __shared__ float lrow[8];

  for (int j = tid; j < 8 * 64; j += 256) {
    const int c = j >> 6, d = j & 63;
    ql[d * 8 + c] = q[(size_t)(c0 + c) * 64 + d];
  }
  __syncthreads();

  {
    float acc[32];
    #pragma unroll
    for (int j = 0; j < 32; ++j) acc[j] = 0.f;
    for (int d = 0; d < 64; ++d) {
      const float* kr = kT + (size_t)d * NCT;
      const float kv0 = kr[tid];
      const float kv1 = kr[tid + 256];
      const float kv2 = kr[tid + 512];
      const float kv3 = kr[tid + 768];
      #pragma unroll
      for (int c4 = 0; c4 < 2; ++c4) {
        const float4 qv = *(const float4*)&ql[d * 8 + c4 * 4];
        const float qa[4] = {qv.x, qv.y, qv.z, qv.w};
        #pragma unroll
        for (int jj = 0; jj < 4; ++jj) {
          const int cc = c4 * 4 + jj;
          acc[cc * 4 + 0] += qa[jj] * kv0;
          acc[cc * 4 + 1] += qa[jj] * kv1;
          acc[cc * 4 + 2] += qa[jj] * kv2;
          acc[cc * 4 + 3] += qa[jj] * kv3;
        }
      }
    }
    #pragma unroll
    for (int cc = 0; cc < 8; ++cc) {
      S[cc * 1024 + tid      ] = acc[cc * 4 + 0] * tscale;
      S[cc * 1024 + tid + 256] = acc[cc * 4 + 1] * tscale;
      S[cc * 1024 + tid + 512] = acc[cc * 4 + 2] * tscale;
      S[cc * 1024 + tid + 768] = acc[cc * 4 + 3] * tscale;
    }
  }
  __syncthreads();

  {
    const int c = tid >> 5, l = tid & 31;
    float* row = &S[c * 1024];
    float mx = -1e30f;
    for (int j = l; j < 1024; j += 32) mx = fmaxf(mx, row[j]);
    #pragma unroll
    for (int msk = 1; msk < 32; msk <<= 1) mx = fmaxf(mx, __shfl_xor(mx, msk, 64));
    float sum = 0.f;
    for (int j = l; j < 1024; j += 32) {
      const float p = __expf(row[j] - mx);
      row[j] = p;
      sum += p;
    }
    #pragma unroll
    for (int msk = 1; msk < 32; msk <<= 1) sum += __shfl_xor(sum, msk, 64);
    if (l == 0) lrow[c] = sum;
  }
  __syncthreads();

  {
    const int xx = tid & 63, cq = tid >> 6;
    float a0 = 0.f, a1 = 0.f;
    for (int e = 0; e < 1024; e += 4) {
      const float v0 = v[(size_t)(e + 0) * 64 + xx];
      const float v1 = v[(size_t)(e + 1) * 64 + xx];
      const float v2 = v[(size_t)(e + 2) * 64 + xx];
      const float v3 = v[(size_t)(e + 3) * 64 + xx];
      const float4 p0 = *(const float4*)&S[(cq * 2 + 0) * 1024 + e];
      const float4 p1 = *(const float4*)&S[(cq * 2 + 1) * 1024 + e];
      a0 += p0.x * v0 + p0.y * v1 + p0.z * v2 + p0.w * v3;
      a1 += p1.x * v0 + p1.y * v1 + p1.z * v2 + p1.w * v3;
    }
    #pragma unroll
    for (int jr = 0; jr < 2; ++jr) {
      const int c = c0 + cq * 2 + jr;
      const float val = ((jr == 0) ? a0 : a1) / lrow[cq * 2 + jr];
      out[((size_t)bn * 256 + (c >> 2)) * 256 + 64 * (c & 3) + xx] = val;
    }
  }
}

extern "C" void kernel_launch(void* const* d_in, const int* in_sizes, int n_in,
                              void* d_out, int out_size, void* d_ws, size_t ws_size,
                              hipStream_t stream) {
  (void)in_sizes; (void)n_in; (void)out_size; (void)ws_size;
  const float* x      = (const float*)d_in[0];
  const float* conv_w = (const float*)d_in[1];
  const float* conv_b = (const float*)d_in[2];
  const float* qW1 = (const float*)d_in[3];
  const float* qb1 = (const float*)d_in[4];
  const float* qW2 = (const float*)d_in[5];
  const float* qb2 = (const float*)d_in[6];
  const float* kW1 = (const float*)d_in[7];
  const float* kb1 = (const float*)d_in[8];
  const float* kW2 = (const float*)d_in[9];
  const float* kb2 = (const float*)d_in[10];
  const float* vW1 = (const float*)d_in[11];
  const float* vb1 = (const float*)d_in[12];
  const float* vW2 = (const float*)d_in[13];
  const float* vb2 = (const float*)d_in[14];
  const float* temp = (const float*)d_in[15];
  float* wsf = (float*)d_ws;
  uint16_t* wsu = (uint16_t*)(wsf + U16_BASE_F);
  float* out = (float*)d_out;

  k1_G<<<dim3(1606), dim3(64), 0, stream>>>(x, qW1, kW1, vW1,
      conv_w, qW2, kW2, vW2, wsf, wsu);
  k2_mfma<<<dim3(1536), dim3(256), 0, stream>>>(
      wsu + GP_U, wsu + CW_U, wsu + W2T_U, conv_b,
      qb1, kb1, vb1, qb2, kb2, vb2, wsf);
  k3_attn<<<dim3(1024), dim3(256), 0, stream>>>(wsf, temp, out);
}

// Round 7
// 63.387 us; speedup vs baseline: 2.8327x; 1.4882x over previous
//
#include <hip/hip_runtime.h>
#include <cstdint>

constexpr int NB  = 2;     // batch
constexpr int NCI = 4;     // conv input channels
constexpr int NHH = 256;   // H
constexpr int NWW = 256;   // W
constexpr int NCT = 1024;  // conv output channels

// ---------------- workspace layout ----------------
// float region: just the W1 column sums
constexpr size_t SW1F = 0;            // 48 floats
constexpr size_t U16_BASE_F = 48;     // u16 region starts here (192 B, 16B-aligned)
// u16 offsets (relative to wsu):
constexpr size_t GP_U  = 0;           // G'bf [m][b][i][dx][r][258]
constexpr size_t CW_U  = 297216;      // CW_bf [o][40]
constexpr size_t W2T_U = 338176;      // W2T_bf [m][s][h]
constexpr size_t QU_O  = 350464;      // Q  bf16 [bn][o][xsp]
constexpr size_t KU_O  = 874752;      // K  bf16 [bn][o][xsp]
constexpr size_t VT_O  = 1399040;     // V^T bf16 [bn][xsp][o]

typedef __attribute__((ext_vector_type(8))) short bf16x8;
typedef __attribute__((ext_vector_type(4))) float f32x4;

__device__ __forceinline__ uint16_t f2bf(float x) {
  uint32_t u = __float_as_uint(x);
  return (uint16_t)((u + 0x7FFFu + ((u >> 16) & 1u)) >> 16);   // RNE
}
__device__ __forceinline__ uint32_t pk2bf(float a, float b) {  // lo=bf(a), hi=bf(b)
  const uint32_t au = __float_as_uint(a) + 0x8000u;
  const uint32_t bu = __float_as_uint(b) + 0x8000u;
  return __builtin_amdgcn_perm(bu, au, 0x07060302u);
}
__device__ __forceinline__ float sigmoid_f(float v) {
  return __builtin_amdgcn_rcpf(1.0f + __expf(-v));
}

// K1: G'bf[m][b][i][dx][r][1+h] = bf16( sum_w x_pad[b,i,h,w+dx-1] * W1_m[w,r] )
// plus sw1 sums, plus CW_bf / W2T_bf prep blocks.  (unchanged from R6)
__global__ __launch_bounds__(64) void k1_G(
    const float* __restrict__ x,
    const float* __restrict__ qW1, const float* __restrict__ kW1,
    const float* __restrict__ vW1,
    const float* __restrict__ conv_w,
    const float* __restrict__ qW2, const float* __restrict__ kW2,
    const float* __restrict__ vW2,
    float* __restrict__ wsf, uint16_t* __restrict__ wsu) {
  const int tid = threadIdx.x;
  const int NBLK = 3 * NB * NCI * (NHH / 4);   // 1536
  int bid = blockIdx.x;

  if (bid >= NBLK + 3 + 64) {                  // W2T_bf prep (3 blocks)
    const int m = bid - (NBLK + 3 + 64);
    const float* W2 = (m == 0) ? qW2 : (m == 1) ? kW2 : vW2;
    for (int u = 0; u < 64; ++u) {
      const int idx = tid * 64 + u;            // 4096 = 16 s x 256 h
      const int s = idx >> 8, h = idx & 255;
      wsu[W2T_U + (size_t)m * 4096 + s * 256 + h] = f2bf(W2[h * 16 + s]);
    }
    return;
  }
  if (bid >= NBLK + 3) {                       // CW_bf prep (64 blocks x 16 o)
    const int p = bid - (NBLK + 3);
    const int o = p * 16 + (tid >> 2);
    const int ks = (tid & 3) * 10;
    for (int u = 0; u < 10; ++u) {
      const int k = ks + u;
      wsu[CW_U + (size_t)o * 40 + k] = (k < 36) ? f2bf(conv_w[o * 36 + k]) : (uint16_t)0;
    }
    return;
  }
  if (bid >= NBLK) {                           // sw1 column sums
    int m = bid - NBLK;
    if (tid < 16) {
      const float* W1 = (m == 0) ? qW1 : (m == 1) ? kW1 : vW1;
      float s = 0.f;
      for (int w = 0; w < 256; ++w) s += W1[w * 16 + tid];
      wsf[SW1F + m * 16 + tid] = s;
    }
    return;
  }

  const int m  = bid / (NB * NCI * (NHH / 4));
  int rem      = bid % (NB * NCI * (NHH / 4));
  const int b  = rem / (NCI * (NHH / 4));
  rem          = rem % (NCI * (NHH / 4));
  const int i  = rem / (NHH / 4);
  const int h0 = (rem % (NHH / 4)) * 4;
  const int mb = m * NB + b;

  const float* W1 = (m == 0) ? qW1 : (m == 1) ? kW1 : vW1;

  __shared__ float W1l[16 * 260];
  __shared__ float xlb[4][260];

  for (int idx4 = tid; idx4 < 1024; idx4 += 64) {
    const float4 t = ((const float4*)W1)[idx4];
    const int w = idx4 >> 2, r0 = (idx4 & 3) * 4;
    W1l[(r0 + 0) * 260 + w] = t.x;
    W1l[(r0 + 1) * 260 + w] = t.y;
    W1l[(r0 + 2) * 260 + w] = t.z;
    W1l[(r0 + 3) * 260 + w] = t.w;
  }
  const float* xbase = x + ((size_t)(b * NCI + i) * NHH + h0) * NWW;
  for (int idx = tid; idx < 4 * 256; idx += 64) {
    const int rr = idx >> 8, w = idx & 255;
    xlb[rr][1 + w] = xbase[rr * NWW + w];
  }
  if (tid < 4) {
    xlb[tid][0] = 0.f; xlb[tid][257] = 0.f; xlb[tid][258] = 0.f; xlb[tid][259] = 0.f;
  }
  __syncthreads();

  // pad rows hp=0 and hp=257 (zeros)
  if (h0 == 0 && tid < 48) {
    const int dxp = tid >> 4, rp = tid & 15;
    wsu[GP_U + ((size_t)((mb * 4 + i) * 3 + dxp) * 16 + rp) * 258 + 0] = 0;
  }
  if (h0 == 252 && tid < 48) {
    const int dxp = tid >> 4, rp = tid & 15;
    wsu[GP_U + ((size_t)((mb * 4 + i) * 3 + dxp) * 16 + rp) * 258 + 257] = 0;
  }

  const int wc = tid >> 4, r = tid & 15;
  const int w0 = wc * 64;
  const size_t gb0 = GP_U + ((size_t)((mb * 4 + i) * 3 + 0) * 16 + r) * 258;

  #pragma unroll
  for (int rr = 0; rr < 4; ++rr) {
    const float* xl = xlb[rr];
    float a0 = 0.f, a1 = 0.f, a2 = 0.f;
    float4 cur = *(const float4*)&xl[w0];
    #pragma unroll 4
    for (int w = w0; w < w0 + 64; w += 4) {
      const float4 nxt = *(const float4*)&xl[w + 4];
      const float4 w1  = *(const float4*)&W1l[r * 260 + w];
      a0 += w1.x * cur.x + w1.y * cur.y + w1.z * cur.z + w1.w * cur.w;
      a1 += w1.x * cur.y + w1.y * cur.z + w1.z * cur.w + w1.w * nxt.x;
      a2 += w1.x * cur.z + w1.y * cur.w + w1.z * nxt.x + w1.w * nxt.y;
      cur = nxt;
    }
    a0 += __shfl_xor(a0, 16, 64); a0 += __shfl_xor(a0, 32, 64);
    a1 += __shfl_xor(a1, 16, 64); a1 += __shfl_xor(a1, 32, 64);
    a2 += __shfl_xor(a2, 16, 64); a2 += __shfl_xor(a2, 32, 64);
    if (wc == 0) {
      const int hp = 1 + h0 + rr;
      wsu[gb0 + hp]        = f2bf(a0);   // dx = 0
      wsu[gb0 + 4128 + hp] = f2bf(a1);   // dx = 1
      wsu[gb0 + 8256 + hp] = f2bf(a2);   // dx = 2
    }
  }
}

// K2 (MFMA): as R6 but epilogue stores bf16: Q,K [bn][o][xsp], V^T [bn][xsp][o].
// grid 1536 = 6 mb x 16 og x 16 r, block 256 = 4 waves.
__global__ __launch_bounds__(256, 4) void k2_mfma(
    const uint16_t* __restrict__ gp, const uint16_t* __restrict__ cwbf,
    const uint16_t* __restrict__ w2t,
    const float* __restrict__ conv_b,
    const float* __restrict__ qb1, const float* __restrict__ kb1, const float* __restrict__ vb1,
    const float* __restrict__ qb2, const float* __restrict__ kb2, const float* __restrict__ vb2,
    const float* __restrict__ wsf, uint16_t* __restrict__ wsu) {
  const int tid = threadIdx.x;
  const int bid = blockIdx.x;
  const int r  = bid & 15;
  const int og = (bid >> 4) & 15;
  const int mb = bid >> 8;            // 0..5
  const int m  = mb >> 1, b = mb & 1;

  const int wv  = tid >> 6;
  const int l   = tid & 63;
  const int l15 = l & 15;
  const int lg  = l >> 4;

  __shared__ uint16_t GS[256 * 40];     // [h][k]
  __shared__ uint16_t y1l[4][16 * 72];  // per-wave [o16][h64+8pad]

  {
    const int h = tid;
    uint16_t* gsrow = &GS[h * 40];
    #pragma unroll
    for (int i = 0; i < 4; ++i) {
      #pragma unroll
      for (int dx = 0; dx < 3; ++dx) {
        const uint16_t* g = gp + ((size_t)((mb * 4 + i) * 3 + dx) * 16 + r) * 258 + h;
        gsrow[i * 9 + 0 * 3 + dx] = g[0];
        gsrow[i * 9 + 1 * 3 + dx] = g[1];
        gsrow[i * 9 + 2 * 3 + dx] = g[2];
      }
    }
    gsrow[36] = 0; gsrow[37] = 0; gsrow[38] = 0; gsrow[39] = 0;
  }
  __syncthreads();

  const float* b1 = (m == 0) ? qb1 : (m == 1) ? kb1 : vb1;
  const float* b2 = (m == 0) ? qb2 : (m == 1) ? kb2 : vb2;

  const int o_blk = og * 64 + wv * 16;

  const uint16_t* cwrow = cwbf + (size_t)(o_blk + l15) * 40;
  bf16x8 cw0 = *(const bf16x8*)(cwrow + lg * 8);
  bf16x8 cw1 = {0,0,0,0,0,0,0,0};
  if (lg == 0) cw1 = *(const bf16x8*)(cwrow + 32);

  const uint16_t* w2row = w2t + (size_t)m * 4096 + (size_t)l15 * 256 + lg * 8;
  bf16x8 w2f0 = *(const bf16x8*)(w2row + 0 * 32);
  bf16x8 w2f1 = *(const bf16x8*)(w2row + 1 * 32);
  bf16x8 w2f2 = *(const bf16x8*)(w2row + 2 * 32);
  bf16x8 w2f3 = *(const bf16x8*)(w2row + 3 * 32);
  bf16x8 w2f4 = *(const bf16x8*)(w2row + 4 * 32);
  bf16x8 w2f5 = *(const bf16x8*)(w2row + 5 * 32);
  bf16x8 w2f6 = *(const bf16x8*)(w2row + 6 * 32);
  bf16x8 w2f7 = *(const bf16x8*)(w2row + 7 * 32);

  const float sw1r = wsf[SW1F + m * 16 + r];
  const float b1r  = b1[r];
  const float cbv  = conv_b[o_blk + l15];
  const float bias1 = cbv * sw1r + b1r;
  const float b2v  = b2[l15];

  uint16_t* yw = &y1l[wv][0];
  f32x4 acc2 = {0.f, 0.f, 0.f, 0.f};

  #pragma unroll
  for (int cc = 0; cc < 4; ++cc) {
    #pragma unroll
    for (int ct = 0; ct < 4; ++ct) {
      const uint16_t* arow = &GS[(cc * 64 + ct * 16 + l15) * 40];
      bf16x8 a0 = *(const bf16x8*)(arow + lg * 8);
      bf16x8 a1 = {0,0,0,0,0,0,0,0};
      if (lg == 0) a1 = *(const bf16x8*)(arow + 32);
      f32x4 d = {0.f, 0.f, 0.f, 0.f};
      d = __builtin_amdgcn_mfma_f32_16x16x32_bf16(a0, cw0, d, 0, 0, 0);
      d = __builtin_amdgcn_mfma_f32_16x16x32_bf16(a1, cw1, d, 0, 0, 0);
      const float y0 = sigmoid_f(d[0] + bias1);
      const float y1 = sigmoid_f(d[1] + bias1);
      const float y2 = sigmoid_f(d[2] + bias1);
      const float y3 = sigmoid_f(d[3] + bias1);
      uint32_t* yd = (uint32_t*)&yw[l15 * 72 + ct * 16 + lg * 4];
      yd[0] = pk2bf(y0, y1);
      yd[1] = pk2bf(y2, y3);
    }
    {
      const uint16_t* yrow = &yw[l15 * 72 + lg * 8];
      bf16x8 ya0 = *(const bf16x8*)(yrow + 0);
      bf16x8 ya1 = *(const bf16x8*)(yrow + 32);
      if (cc == 0) {
        acc2 = __builtin_amdgcn_mfma_f32_16x16x32_bf16(ya0, w2f0, acc2, 0, 0, 0);
        acc2 = __builtin_amdgcn_mfma_f32_16x16x32_bf16(ya1, w2f1, acc2, 0, 0, 0);
      } else if (cc == 1) {
        acc2 = __builtin_amdgcn_mfma_f32_16x16x32_bf16(ya0, w2f2, acc2, 0, 0, 0);
        acc2 = __builtin_amdgcn_mfma_f32_16x16x32_bf16(ya1, w2f3, acc2, 0, 0, 0);
      } else if (cc == 2) {
        acc2 = __builtin_amdgcn_mfma_f32_16x16x32_bf16(ya0, w2f4, acc2, 0, 0, 0);
        acc2 = __builtin_amdgcn_mfma_f32_16x16x32_bf16(ya1, w2f5, acc2, 0, 0, 0);
      } else {
        acc2 = __builtin_amdgcn_mfma_f32_16x16x32_bf16(ya0, w2f6, acc2, 0, 0, 0);
        acc2 = __builtin_amdgcn_mfma_f32_16x16x32_bf16(ya1, w2f7, acc2, 0, 0, 0);
      }
    }
  }

  // epilogue: y2 = sigmoid(acc2 + b2) -> bf16 q/k/vT
  const int s   = l15;
  const int n   = (s & 1) * 2 + (r & 1);
  const int xsp = (s >> 1) * 8 + (r >> 1);
  const int bn  = b * 4 + n;
  uint16_t* qk = wsu + ((m == 0) ? QU_O : KU_O);
  uint16_t* vT = wsu + VT_O;
  #pragma unroll
  for (int p = 0; p < 4; ++p) {
    const int o = o_blk + lg * 4 + p;
    const uint16_t y2 = f2bf(sigmoid_f(acc2[p] + b2v));
    if (m == 2) vT[((size_t)bn * 64 + xsp) * 1024 + o] = y2;
    else        qk[((size_t)bn * 1024 + o) * 64 + xsp] = y2;
  }
}

// K3 (MFMA flash): grid 512 = 8 bn x 64 c-tiles, block 64 (1 wave, 16 c).
// Per 64-e tile: S^T = mfma(K, Q) -> online softmax (lane-local per c) ->
// P bf16 via wave-private LDS -> O^T += mfma(V^T, P). No barriers.
__global__ __launch_bounds__(64) void k3_attn(
    const uint16_t* __restrict__ qu, const uint16_t* __restrict__ ku,
    const uint16_t* __restrict__ vtu, const float* __restrict__ temp,
    float* __restrict__ out) {
  const int l   = threadIdx.x;
  const int l15 = l & 15, lg = l >> 4;
  const int bn    = blockIdx.x >> 6;
  const int cbase = (blockIdx.x & 63) * 16;
  const float tscale = temp[bn & 3];

  __shared__ uint16_t P_lds[2][16 * 72];   // [c][64 e + 8 pad], double-buffered

  // Q B-frags: B[k=d][col=c] from Q[bn][c][d]
  const uint16_t* qrow = qu + (size_t)(bn * 1024 + cbase + l15) * 64 + lg * 8;
  const bf16x8 qf0 = *(const bf16x8*)(qrow);
  const bf16x8 qf1 = *(const bf16x8*)(qrow + 32);

  const uint16_t* kb = ku  + (size_t)bn * 65536 + lg * 8;
  const uint16_t* vb = vtu + (size_t)bn * 65536 + lg * 8;

  f32x4 o0 = {0.f,0.f,0.f,0.f}, o1 = o0, o2 = o0, o3 = o0;  // O^T[x][c], 4 x-tiles
  float mrun = -3.0e38f, lrun = 0.f;

  #pragma unroll 2
  for (int et = 0; et < 16; ++et) {
    const int e0 = et * 64;
    uint16_t* pl = &P_lds[et & 1][0];

    // ---- S^T tile: D[e][c] = sum_d K[e][d] Q[c][d], 4 e-subtiles ----
    f32x4 s0 = {0.f,0.f,0.f,0.f}, s1 = s0, s2 = s0, s3 = s0;
    {
      const uint16_t* kr0 = kb + (size_t)(e0 +  0 + l15) * 64;
      const uint16_t* kr1 = kb + (size_t)(e0 + 16 + l15) * 64;
      const uint16_t* kr2 = kb + (size_t)(e0 + 32 + l15) * 64;
      const uint16_t* kr3 = kb + (size_t)(e0 + 48 + l15) * 64;
      const bf16x8 ka0 = *(const bf16x8*)(kr0);
      const bf16x8 kb0 = *(const bf16x8*)(kr0 + 32);
      const bf16x8 ka1 = *(const bf16x8*)(kr1);
      const bf16x8 kb1_ = *(const bf16x8*)(kr1 + 32);
      const bf16x8 ka2 = *(const bf16x8*)(kr2);
      const bf16x8 kb2_ = *(const bf16x8*)(kr2 + 32);
      const bf16x8 ka3 = *(const bf16x8*)(kr3);
      const bf16x8 kb3_ = *(const bf16x8*)(kr3 + 32);
      s0 = __builtin_amdgcn_mfma_f32_16x16x32_bf16(ka0, qf0, s0, 0,0,0);
      s0 = __builtin_amdgcn_mfma_f32_16x16x32_bf16(kb0, qf1, s0, 0,0,0);
      s1 = __builtin_amdgcn_mfma_f32_16x16x32_bf16(ka1, qf0, s1, 0,0,0);
      s1 = __builtin_amdgcn_mfma_f32_16x16x32_bf16(kb1_, qf1, s1, 0,0,0);
      s2 = __builtin_amdgcn_mfma_f32_16x16x32_bf16(ka2, qf0, s2, 0,0,0);
      s2 = __builtin_amdgcn_mfma_f32_16x16x32_bf16(kb2_, qf1, s2, 0,0,0);
      s3 = __builtin_amdgcn_mfma_f32_16x16x32_bf16(ka3, qf0, s3, 0,0,0);
      s3 = __builtin_amdgcn_mfma_f32_16x16x32_bf16(kb3_, qf1, s3, 0,0,0);
    }
    #pragma unroll
    for (int p = 0; p < 4; ++p) {
      s0[p] *= tscale; s1[p] *= tscale; s2[p] *= tscale; s3[p] *= tscale;
    }

    // ---- online softmax per c (col = l15): regs + lanes {l15+16g} ----
    float t0 = fmaxf(fmaxf(s0[0], s0[1]), fmaxf(s0[2], s0[3]));
    float t1 = fmaxf(fmaxf(s1[0], s1[1]), fmaxf(s1[2], s1[3]));
    float t2 = fmaxf(fmaxf(s2[0], s2[1]), fmaxf(s2[2], s2[3]));
    float t3 = fmaxf(fmaxf(s3[0], s3[1]), fmaxf(s3[2], s3[3]));
    float tmax = fmaxf(fmaxf(t0, t1), fmaxf(t2, t3));
    tmax = fmaxf(tmax, __shfl_xor(tmax, 16, 64));
    tmax = fmaxf(tmax, __shfl_xor(tmax, 32, 64));
    const float mnew = fmaxf(mrun, tmax);
    const float scl  = __expf(mrun - mnew);
    float psum = 0.f;
    #pragma unroll
    for (int p = 0; p < 4; ++p) { s0[p] = __expf(s0[p] - mnew); psum += s0[p]; }
    #pragma unroll
    for (int p = 0; p < 4; ++p) { s1[p] = __expf(s1[p] - mnew); psum += s1[p]; }
    #pragma unroll
    for (int p = 0; p < 4; ++p) { s2[p] = __expf(s2[p] - mnew); psum += s2[p]; }
    #pragma unroll
    for (int p = 0; p < 4; ++p) { s3[p] = __expf(s3[p] - mnew); psum += s3[p]; }
    psum += __shfl_xor(psum, 16, 64);
    psum += __shfl_xor(psum, 32, 64);
    lrun = lrun * scl + psum;
    mrun = mnew;

    // ---- pack P -> LDS [c][e] (e_local = es*16 + lg*4 + p) ----
    {
      uint32_t* p0w = (uint32_t*)&pl[l15 * 72 +  0 + lg * 4];
      uint32_t* p1w = (uint32_t*)&pl[l15 * 72 + 16 + lg * 4];
      uint32_t* p2w = (uint32_t*)&pl[l15 * 72 + 32 + lg * 4];
      uint32_t* p3w = (uint32_t*)&pl[l15 * 72 + 48 + lg * 4];
      p0w[0] = pk2bf(s0[0], s0[1]); p0w[1] = pk2bf(s0[2], s0[3]);
      p1w[0] = pk2bf(s1[0], s1[1]); p1w[1] = pk2bf(s1[2], s1[3]);
      p2w[0] = pk2bf(s2[0], s2[1]); p2w[1] = pk2bf(s2[2], s2[3]);
      p3w[0] = pk2bf(s3[0], s3[1]); p3w[1] = pk2bf(s3[2], s3[3]);
    }

    // ---- rescale O^T by scl (per-c = lane-local) ----
    #pragma unroll
    for (int p = 0; p < 4; ++p) {
      o0[p] *= scl; o1[p] *= scl; o2[p] *= scl; o3[p] *= scl;
    }

    // ---- PV: O^T[x][c] += sum_e V^T[x][e] P[e][c] ----
    {
      const bf16x8 pb0 = *(const bf16x8*)&pl[l15 * 72 +  0 + lg * 8];
      const bf16x8 pb1 = *(const bf16x8*)&pl[l15 * 72 + 32 + lg * 8];
      const uint16_t* vr0 = vb + (size_t)( 0 + l15) * 1024 + e0;
      const uint16_t* vr1 = vb + (size_t)(16 + l15) * 1024 + e0;
      const uint16_t* vr2 = vb + (size_t)(32 + l15) * 1024 + e0;
      const uint16_t* vr3 = vb + (size_t)(48 + l15) * 1024 + e0;
      bf16x8 va;
      va = *(const bf16x8*)(vr0);      o0 = __builtin_amdgcn_mfma_f32_16x16x32_bf16(va, pb0, o0, 0,0,0);
      va = *(const bf16x8*)(vr0 + 32); o0 = __builtin_amdgcn_mfma_f32_16x16x32_bf16(va, pb1, o0, 0,0,0);
      va = *(const bf16x8*)(vr1);      o1 = __builtin_amdgcn_mfma_f32_16x16x32_bf16(va, pb0, o1, 0,0,0);
      va = *(const bf16x8*)(vr1 + 32); o1 = __builtin_amdgcn_mfma_f32_16x16x32_bf16(va, pb1, o1, 0,0,0);
      va = *(const bf16x8*)(vr2);      o2 = __builtin_amdgcn_mfma_f32_16x16x32_bf16(va, pb0, o2, 0,0,0);
      va = *(const bf16x8*)(vr2 + 32); o2 = __builtin_amdgcn_mfma_f32_16x16x32_bf16(va, pb1, o2, 0,0,0);
      va = *(const bf16x8*)(vr3);      o3 = __builtin_amdgcn_mfma_f32_16x16x32_bf16(va, pb0, o3, 0,0,0);
      va = *(const bf16x8*)(vr3 + 32); o3 = __builtin_amdgcn_mfma_f32_16x16x32_bf16(va, pb1, o3, 0,0,0);
    }
  }

  // ---- normalize (per-c = lane-local) and write out ----
  const float rl = __builtin_amdgcn_rcpf(lrun);
  const int C = cbase + l15;
  float* ob = out + ((size_t)bn * 256 + (C >> 2)) * 256 + (C & 3) * 64;
  #pragma unroll
  for (int p = 0; p < 4; ++p) {
    ob[ 0 + lg * 4 + p] = o0[p] * rl;
    ob[16 + lg * 4 + p] = o1[p] * rl;
    ob[32 + lg * 4 + p] = o2[p] * rl;
    ob[48 + lg * 4 + p] = o3[p] * rl;
  }
}

extern "C" void kernel_launch(void* const* d_in, const int* in_sizes, int n_in,
                              void* d_out, int out_size, void* d_ws, size_t ws_size,
                              hipStream_t stream) {
  (void)in_sizes; (void)n_in; (void)out_size; (void)ws_size;
  const float* x      = (const float*)d_in[0];
  const float* conv_w = (const float*)d_in[1];
  const float* conv_b = (const float*)d_in[2];
  const float* qW1 = (const float*)d_in[3];
  const float* qb1 = (const float*)d_in[4];
  const float* qW2 = (const float*)d_in[5];
  const float* qb2 = (const float*)d_in[6];
  const float* kW1 = (const float*)d_in[7];
  const float* kb1 = (const float*)d_in[8];
  const float* kW2 = (const float*)d_in[9];
  const float* kb2 = (const float*)d_in[10];
  const float* vW1 = (const float*)d_in[11];
  const float* vb1 = (const float*)d_in[12];
  const float* vW2 = (const float*)d_in[13];
  const float* vb2 = (const float*)d_in[14];
  const float* temp = (const float*)d_in[15];
  float* wsf = (float*)d_ws;
  uint16_t* wsu = (uint16_t*)(wsf + U16_BASE_F);
  float* out = (float*)d_out;

  k1_G<<<dim3(1606), dim3(64), 0, stream>>>(x, qW1, kW1, vW1,
      conv_w, qW2, kW2, vW2, wsf, wsu);
  k2_mfma<<<dim3(1536), dim3(256), 0, stream>>>(
      wsu + GP_U, wsu + CW_U, wsu + W2T_U, conv_b,
      qb1, kb1, vb1, qb2, kb2, vb2, wsf, wsu);
  k3_attn<<<dim3(512), dim3(64), 0, stream>>>(
      wsu + QU_O, wsu + KU_O, wsu + VT_O, temp, out);
}

// Round 8
// 53.922 us; speedup vs baseline: 3.3299x; 1.1755x over previous
//
#include <hip/hip_runtime.h>
#include <cstdint>

constexpr int NB  = 2;     // batch
constexpr int NCI = 4;     // conv input channels
constexpr int NHH = 256;   // H
constexpr int NWW = 256;   // W
constexpr int NCT = 1024;  // conv output channels

// ---------------- workspace layout ----------------
// float region: W1 column sums, then (after u16 region) attention partials
constexpr size_t SW1F = 0;            // 48 floats
constexpr size_t U16_BASE_F = 48;     // u16 region starts here
// u16 offsets (relative to wsu):
constexpr size_t GP_U  = 0;           // G'bf [m][b][i][dx][r][258]
constexpr size_t CW_U  = 297216;      // CW_bf [o][40]
constexpr size_t W2T_U = 338176;      // W2T_bf [m][s][h]
constexpr size_t QU_O  = 350464;      // Q  bf16 [bn][o][xsp]
constexpr size_t KU_O  = 874752;      // K  bf16 [bn][o][xsp]
constexpr size_t VT_O  = 1399040;     // V^T bf16 [bn][xsp][o]
// u16 region ends at 1923328 u16 = 961664 floats
constexpr size_t PART_O_F  = 961712;              // 2048 tasks x 1024 f32
constexpr size_t PART_ML_F = PART_O_F + 2097152;  // 2048 tasks x (16 m + 16 l)

typedef __attribute__((ext_vector_type(8))) short bf16x8;
typedef __attribute__((ext_vector_type(4))) float f32x4;

__device__ __forceinline__ uint16_t f2bf(float x) {
  uint32_t u = __float_as_uint(x);
  return (uint16_t)((u + 0x7FFFu + ((u >> 16) & 1u)) >> 16);   // RNE
}
__device__ __forceinline__ uint32_t pk2bf(float a, float b) {  // lo=bf(a), hi=bf(b)
  const uint32_t au = __float_as_uint(a) + 0x8000u;
  const uint32_t bu = __float_as_uint(b) + 0x8000u;
  return __builtin_amdgcn_perm(bu, au, 0x07060302u);
}
__device__ __forceinline__ float sigmoid_f(float v) {
  return __builtin_amdgcn_rcpf(1.0f + __expf(-v));
}

// K1: G'bf[m][b][i][dx][r][1+h] = bf16( sum_w x_pad[b,i,h,w+dx-1] * W1_m[w,r] )
// plus sw1 sums, plus CW_bf / W2T_bf prep blocks.  (unchanged)
__global__ __launch_bounds__(64) void k1_G(
    const float* __restrict__ x,
    const float* __restrict__ qW1, const float* __restrict__ kW1,
    const float* __restrict__ vW1,
    const float* __restrict__ conv_w,
    const float* __restrict__ qW2, const float* __restrict__ kW2,
    const float* __restrict__ vW2,
    float* __restrict__ wsf, uint16_t* __restrict__ wsu) {
  const int tid = threadIdx.x;
  const int NBLK = 3 * NB * NCI * (NHH / 4);   // 1536
  int bid = blockIdx.x;

  if (bid >= NBLK + 3 + 64) {                  // W2T_bf prep (3 blocks)
    const int m = bid - (NBLK + 3 + 64);
    const float* W2 = (m == 0) ? qW2 : (m == 1) ? kW2 : vW2;
    for (int u = 0; u < 64; ++u) {
      const int idx = tid * 64 + u;            // 4096 = 16 s x 256 h
      const int s = idx >> 8, h = idx & 255;
      wsu[W2T_U + (size_t)m * 4096 + s * 256 + h] = f2bf(W2[h * 16 + s]);
    }
    return;
  }
  if (bid >= NBLK + 3) {                       // CW_bf prep (64 blocks x 16 o)
    const int p = bid - (NBLK + 3);
    const int o = p * 16 + (tid >> 2);
    const int ks = (tid & 3) * 10;
    for (int u = 0; u < 10; ++u) {
      const int k = ks + u;
      wsu[CW_U + (size_t)o * 40 + k] = (k < 36) ? f2bf(conv_w[o * 36 + k]) : (uint16_t)0;
    }
    return;
  }
  if (bid >= NBLK) {                           // sw1 column sums
    int m = bid - NBLK;
    if (tid < 16) {
      const float* W1 = (m == 0) ? qW1 : (m == 1) ? kW1 : vW1;
      float s = 0.f;
      for (int w = 0; w < 256; ++w) s += W1[w * 16 + tid];
      wsf[SW1F + m * 16 + tid] = s;
    }
    return;
  }

  const int m  = bid / (NB * NCI * (NHH / 4));
  int rem      = bid % (NB * NCI * (NHH / 4));
  const int b  = rem / (NCI * (NHH / 4));
  rem          = rem % (NCI * (NHH / 4));
  const int i  = rem / (NHH / 4);
  const int h0 = (rem % (NHH / 4)) * 4;
  const int mb = m * NB + b;

  const float* W1 = (m == 0) ? qW1 : (m == 1) ? kW1 : vW1;

  __shared__ float W1l[16 * 260];
  __shared__ float xlb[4][260];

  for (int idx4 = tid; idx4 < 1024; idx4 += 64) {
    const float4 t = ((const float4*)W1)[idx4];
    const int w = idx4 >> 2, r0 = (idx4 & 3) * 4;
    W1l[(r0 + 0) * 260 + w] = t.x;
    W1l[(r0 + 1) * 260 + w] = t.y;
    W1l[(r0 + 2) * 260 + w] = t.z;
    W1l[(r0 + 3) * 260 + w] = t.w;
  }
  const float* xbase = x + ((size_t)(b * NCI + i) * NHH + h0) * NWW;
  for (int idx = tid; idx < 4 * 256; idx += 64) {
    const int rr = idx >> 8, w = idx & 255;
    xlb[rr][1 + w] = xbase[rr * NWW + w];
  }
  if (tid < 4) {
    xlb[tid][0] = 0.f; xlb[tid][257] = 0.f; xlb[tid][258] = 0.f; xlb[tid][259] = 0.f;
  }
  __syncthreads();

  // pad rows hp=0 and hp=257 (zeros)
  if (h0 == 0 && tid < 48) {
    const int dxp = tid >> 4, rp = tid & 15;
    wsu[GP_U + ((size_t)((mb * 4 + i) * 3 + dxp) * 16 + rp) * 258 + 0] = 0;
  }
  if (h0 == 252 && tid < 48) {
    const int dxp = tid >> 4, rp = tid & 15;
    wsu[GP_U + ((size_t)((mb * 4 + i) * 3 + dxp) * 16 + rp) * 258 + 257] = 0;
  }

  const int wc = tid >> 4, r = tid & 15;
  const int w0 = wc * 64;
  const size_t gb0 = GP_U + ((size_t)((mb * 4 + i) * 3 + 0) * 16 + r) * 258;

  #pragma unroll
  for (int rr = 0; rr < 4; ++rr) {
    const float* xl = xlb[rr];
    float a0 = 0.f, a1 = 0.f, a2 = 0.f;
    float4 cur = *(const float4*)&xl[w0];
    #pragma unroll 4
    for (int w = w0; w < w0 + 64; w += 4) {
      const float4 nxt = *(const float4*)&xl[w + 4];
      const float4 w1  = *(const float4*)&W1l[r * 260 + w];
      a0 += w1.x * cur.x + w1.y * cur.y + w1.z * cur.z + w1.w * cur.w;
      a1 += w1.x * cur.y + w1.y * cur.z + w1.z * cur.w + w1.w * nxt.x;
      a2 += w1.x * cur.z + w1.y * cur.w + w1.z * nxt.x + w1.w * nxt.y;
      cur = nxt;
    }
    a0 += __shfl_xor(a0, 16, 64); a0 += __shfl_xor(a0, 32, 64);
    a1 += __shfl_xor(a1, 16, 64); a1 += __shfl_xor(a1, 32, 64);
    a2 += __shfl_xor(a2, 16, 64); a2 += __shfl_xor(a2, 32, 64);
    if (wc == 0) {
      const int hp = 1 + h0 + rr;
      wsu[gb0 + hp]        = f2bf(a0);   // dx = 0
      wsu[gb0 + 4128 + hp] = f2bf(a1);   // dx = 1
      wsu[gb0 + 8256 + hp] = f2bf(a2);   // dx = 2
    }
  }
}

// K2 (MFMA): bf16 epilogue: Q,K [bn][o][xsp], V^T [bn][xsp][o].  (unchanged)
__global__ __launch_bounds__(256, 4) void k2_mfma(
    const uint16_t* __restrict__ gp, const uint16_t* __restrict__ cwbf,
    const uint16_t* __restrict__ w2t,
    const float* __restrict__ conv_b,
    const float* __restrict__ qb1, const float* __restrict__ kb1, const float* __restrict__ vb1,
    const float* __restrict__ qb2, const float* __restrict__ kb2, const float* __restrict__ vb2,
    const float* __restrict__ wsf, uint16_t* __restrict__ wsu) {
  const int tid = threadIdx.x;
  const int bid = blockIdx.x;
  const int r  = bid & 15;
  const int og = (bid >> 4) & 15;
  const int mb = bid >> 8;            // 0..5
  const int m  = mb >> 1, b = mb & 1;

  const int wv  = tid >> 6;
  const int l   = tid & 63;
  const int l15 = l & 15;
  const int lg  = l >> 4;

  __shared__ uint16_t GS[256 * 40];     // [h][k]
  __shared__ uint16_t y1l[4][16 * 72];  // per-wave [o16][h64+8pad]

  {
    const int h = tid;
    uint16_t* gsrow = &GS[h * 40];
    #pragma unroll
    for (int i = 0; i < 4; ++i) {
      #pragma unroll
      for (int dx = 0; dx < 3; ++dx) {
        const uint16_t* g = gp + ((size_t)((mb * 4 + i) * 3 + dx) * 16 + r) * 258 + h;
        gsrow[i * 9 + 0 * 3 + dx] = g[0];
        gsrow[i * 9 + 1 * 3 + dx] = g[1];
        gsrow[i * 9 + 2 * 3 + dx] = g[2];
      }
    }
    gsrow[36] = 0; gsrow[37] = 0; gsrow[38] = 0; gsrow[39] = 0;
  }
  __syncthreads();

  const float* b1 = (m == 0) ? qb1 : (m == 1) ? kb1 : vb1;
  const float* b2 = (m == 0) ? qb2 : (m == 1) ? kb2 : vb2;

  const int o_blk = og * 64 + wv * 16;

  const uint16_t* cwrow = cwbf + (size_t)(o_blk + l15) * 40;
  bf16x8 cw0 = *(const bf16x8*)(cwrow + lg * 8);
  bf16x8 cw1 = {0,0,0,0,0,0,0,0};
  if (lg == 0) cw1 = *(const bf16x8*)(cwrow + 32);

  const uint16_t* w2row = w2t + (size_t)m * 4096 + (size_t)l15 * 256 + lg * 8;
  bf16x8 w2f0 = *(const bf16x8*)(w2row + 0 * 32);
  bf16x8 w2f1 = *(const bf16x8*)(w2row + 1 * 32);
  bf16x8 w2f2 = *(const bf16x8*)(w2row + 2 * 32);
  bf16x8 w2f3 = *(const bf16x8*)(w2row + 3 * 32);
  bf16x8 w2f4 = *(const bf16x8*)(w2row + 4 * 32);
  bf16x8 w2f5 = *(const bf16x8*)(w2row + 5 * 32);
  bf16x8 w2f6 = *(const bf16x8*)(w2row + 6 * 32);
  bf16x8 w2f7 = *(const bf16x8*)(w2row + 7 * 32);

  const float sw1r = wsf[SW1F + m * 16 + r];
  const float b1r  = b1[r];
  const float cbv  = conv_b[o_blk + l15];
  const float bias1 = cbv * sw1r + b1r;
  const float b2v  = b2[l15];

  uint16_t* yw = &y1l[wv][0];
  f32x4 acc2 = {0.f, 0.f, 0.f, 0.f};

  #pragma unroll
  for (int cc = 0; cc < 4; ++cc) {
    #pragma unroll
    for (int ct = 0; ct < 4; ++ct) {
      const uint16_t* arow = &GS[(cc * 64 + ct * 16 + l15) * 40];
      bf16x8 a0 = *(const bf16x8*)(arow + lg * 8);
      bf16x8 a1 = {0,0,0,0,0,0,0,0};
      if (lg == 0) a1 = *(const bf16x8*)(arow + 32);
      f32x4 d = {0.f, 0.f, 0.f, 0.f};
      d = __builtin_amdgcn_mfma_f32_16x16x32_bf16(a0, cw0, d, 0, 0, 0);
      d = __builtin_amdgcn_mfma_f32_16x16x32_bf16(a1, cw1, d, 0, 0, 0);
      const float y0 = sigmoid_f(d[0] + bias1);
      const float y1 = sigmoid_f(d[1] + bias1);
      const float y2 = sigmoid_f(d[2] + bias1);
      const float y3 = sigmoid_f(d[3] + bias1);
      uint32_t* yd = (uint32_t*)&yw[l15 * 72 + ct * 16 + lg * 4];
      yd[0] = pk2bf(y0, y1);
      yd[1] = pk2bf(y2, y3);
    }
    {
      const uint16_t* yrow = &yw[l15 * 72 + lg * 8];
      bf16x8 ya0 = *(const bf16x8*)(yrow + 0);
      bf16x8 ya1 = *(const bf16x8*)(yrow + 32);
      if (cc == 0) {
        acc2 = __builtin_amdgcn_mfma_f32_16x16x32_bf16(ya0, w2f0, acc2, 0, 0, 0);
        acc2 = __builtin_amdgcn_mfma_f32_16x16x32_bf16(ya1, w2f1, acc2, 0, 0, 0);
      } else if (cc == 1) {
        acc2 = __builtin_amdgcn_mfma_f32_16x16x32_bf16(ya0, w2f2, acc2, 0, 0, 0);
        acc2 = __builtin_amdgcn_mfma_f32_16x16x32_bf16(ya1, w2f3, acc2, 0, 0, 0);
      } else if (cc == 2) {
        acc2 = __builtin_amdgcn_mfma_f32_16x16x32_bf16(ya0, w2f4, acc2, 0, 0, 0);
        acc2 = __builtin_amdgcn_mfma_f32_16x16x32_bf16(ya1, w2f5, acc2, 0, 0, 0);
      } else {
        acc2 = __builtin_amdgcn_mfma_f32_16x16x32_bf16(ya0, w2f6, acc2, 0, 0, 0);
        acc2 = __builtin_amdgcn_mfma_f32_16x16x32_bf16(ya1, w2f7, acc2, 0, 0, 0);
      }
    }
  }

  // epilogue: y2 = sigmoid(acc2 + b2) -> bf16 q/k/vT
  const int s   = l15;
  const int n   = (s & 1) * 2 + (r & 1);
  const int xsp = (s >> 1) * 8 + (r >> 1);
  const int bn  = b * 4 + n;
  uint16_t* qk = wsu + ((m == 0) ? QU_O : KU_O);
  uint16_t* vT = wsu + VT_O;
  #pragma unroll
  for (int p = 0; p < 4; ++p) {
    const int o = o_blk + lg * 4 + p;
    const uint16_t y2 = f2bf(sigmoid_f(acc2[p] + b2v));
    if (m == 2) vT[((size_t)bn * 64 + xsp) * 1024 + o] = y2;
    else        qk[((size_t)bn * 1024 + o) * 64 + xsp] = y2;
  }
}

// K3 (split-KV flash): grid 2048 = 8 bn x 64 c-tiles x 4 e-chunks, block 64.
// Per 64-e tile: S^T = mfma(K, Q) -> online softmax -> P bf16 (wave LDS) ->
// O^T += mfma(V^T, P). Writes unnormalized partial O^T + (m, l) per task.
__global__ __launch_bounds__(64) void k3_attn(
    const uint16_t* __restrict__ qu, const uint16_t* __restrict__ ku,
    const uint16_t* __restrict__ vtu, const float* __restrict__ temp,
    float* __restrict__ wsf) {
  const int l   = threadIdx.x;
  const int l15 = l & 15, lg = l >> 4;
  const int bid = blockIdx.x;
  const int bn = bid >> 8;
  const int ct = (bid >> 2) & 63;
  const int ec = bid & 3;
  const int cbase = ct * 16;
  const float tscale = temp[bn & 3];

  __shared__ uint16_t P_lds[2][16 * 72];   // [c][64 e + 8 pad], double-buffered

  // Q B-frags: B[k=d][col=c] from Q[bn][c][d]
  const uint16_t* qrow = qu + (size_t)(bn * 1024 + cbase + l15) * 64 + lg * 8;
  const bf16x8 qf0 = *(const bf16x8*)(qrow);
  const bf16x8 qf1 = *(const bf16x8*)(qrow + 32);

  const uint16_t* kb = ku  + (size_t)bn * 65536 + lg * 8;
  const uint16_t* vb = vtu + (size_t)bn * 65536 + lg * 8;

  f32x4 o0 = {0.f,0.f,0.f,0.f}, o1 = o0, o2 = o0, o3 = o0;  // O^T[x][c], 4 x-tiles
  float mrun = -3.0e38f, lrun = 0.f;

  #pragma unroll
  for (int et = 0; et < 4; ++et) {
    const int e0 = ec * 256 + et * 64;
    uint16_t* pl = &P_lds[et & 1][0];

    // ---- S^T tile: D[e][c] = sum_d K[e][d] Q[c][d], 4 e-subtiles ----
    f32x4 s0 = {0.f,0.f,0.f,0.f}, s1 = s0, s2 = s0, s3 = s0;
    {
      const uint16_t* kr0 = kb + (size_t)(e0 +  0 + l15) * 64;
      const uint16_t* kr1 = kb + (size_t)(e0 + 16 + l15) * 64;
      const uint16_t* kr2 = kb + (size_t)(e0 + 32 + l15) * 64;
      const uint16_t* kr3 = kb + (size_t)(e0 + 48 + l15) * 64;
      const bf16x8 ka0 = *(const bf16x8*)(kr0);
      const bf16x8 kb0 = *(const bf16x8*)(kr0 + 32);
      const bf16x8 ka1 = *(const bf16x8*)(kr1);
      const bf16x8 kb1_ = *(const bf16x8*)(kr1 + 32);
      const bf16x8 ka2 = *(const bf16x8*)(kr2);
      const bf16x8 kb2_ = *(const bf16x8*)(kr2 + 32);
      const bf16x8 ka3 = *(const bf16x8*)(kr3);
      const bf16x8 kb3_ = *(const bf16x8*)(kr3 + 32);
      s0 = __builtin_amdgcn_mfma_f32_16x16x32_bf16(ka0, qf0, s0, 0,0,0);
      s0 = __builtin_amdgcn_mfma_f32_16x16x32_bf16(kb0, qf1, s0, 0,0,0);
      s1 = __builtin_amdgcn_mfma_f32_16x16x32_bf16(ka1, qf0, s1, 0,0,0);
      s1 = __builtin_amdgcn_mfma_f32_16x16x32_bf16(kb1_, qf1, s1, 0,0,0);
      s2 = __builtin_amdgcn_mfma_f32_16x16x32_bf16(ka2, qf0, s2, 0,0,0);
      s2 = __builtin_amdgcn_mfma_f32_16x16x32_bf16(kb2_, qf1, s2, 0,0,0);
      s3 = __builtin_amdgcn_mfma_f32_16x16x32_bf16(ka3, qf0, s3, 0,0,0);
      s3 = __builtin_amdgcn_mfma_f32_16x16x32_bf16(kb3_, qf1, s3, 0,0,0);
    }
    #pragma unroll
    for (int p = 0; p < 4; ++p) {
      s0[p] *= tscale; s1[p] *= tscale; s2[p] *= tscale; s3[p] *= tscale;
    }

    // ---- online softmax per c (col = l15) ----
    float t0 = fmaxf(fmaxf(s0[0], s0[1]), fmaxf(s0[2], s0[3]));
    float t1 = fmaxf(fmaxf(s1[0], s1[1]), fmaxf(s1[2], s1[3]));
    float t2 = fmaxf(fmaxf(s2[0], s2[1]), fmaxf(s2[2], s2[3]));
    float t3 = fmaxf(fmaxf(s3[0], s3[1]), fmaxf(s3[2], s3[3]));
    float tmax = fmaxf(fmaxf(t0, t1), fmaxf(t2, t3));
    tmax = fmaxf(tmax, __shfl_xor(tmax, 16, 64));
    tmax = fmaxf(tmax, __shfl_xor(tmax, 32, 64));
    const float mnew = fmaxf(mrun, tmax);
    const float scl  = __expf(mrun - mnew);
    float psum = 0.f;
    #pragma unroll
    for (int p = 0; p < 4; ++p) { s0[p] = __expf(s0[p] - mnew); psum += s0[p]; }
    #pragma unroll
    for (int p = 0; p < 4; ++p) { s1[p] = __expf(s1[p] - mnew); psum += s1[p]; }
    #pragma unroll
    for (int p = 0; p < 4; ++p) { s2[p] = __expf(s2[p] - mnew); psum += s2[p]; }
    #pragma unroll
    for (int p = 0; p < 4; ++p) { s3[p] = __expf(s3[p] - mnew); psum += s3[p]; }
    psum += __shfl_xor(psum, 16, 64);
    psum += __shfl_xor(psum, 32, 64);
    lrun = lrun * scl + psum;
    mrun = mnew;

    // ---- pack P -> LDS [c][e] ----
    {
      uint32_t* p0w = (uint32_t*)&pl[l15 * 72 +  0 + lg * 4];
      uint32_t* p1w = (uint32_t*)&pl[l15 * 72 + 16 + lg * 4];
      uint32_t* p2w = (uint32_t*)&pl[l15 * 72 + 32 + lg * 4];
      uint32_t* p3w = (uint32_t*)&pl[l15 * 72 + 48 + lg * 4];
      p0w[0] = pk2bf(s0[0], s0[1]); p0w[1] = pk2bf(s0[2], s0[3]);
      p1w[0] = pk2bf(s1[0], s1[1]); p1w[1] = pk2bf(s1[2], s1[3]);
      p2w[0] = pk2bf(s2[0], s2[1]); p2w[1] = pk2bf(s2[2], s2[3]);
      p3w[0] = pk2bf(s3[0], s3[1]); p3w[1] = pk2bf(s3[2], s3[3]);
    }

    // ---- rescale O^T by scl (per-c = lane-local) ----
    #pragma unroll
    for (int p = 0; p < 4; ++p) {
      o0[p] *= scl; o1[p] *= scl; o2[p] *= scl; o3[p] *= scl;
    }

    // ---- PV: O^T[x][c] += sum_e V^T[x][e] P[e][c] ----
    {
      const bf16x8 pb0 = *(const bf16x8*)&pl[l15 * 72 +  0 + lg * 8];
      const bf16x8 pb1 = *(const bf16x8*)&pl[l15 * 72 + 32 + lg * 8];
      const uint16_t* vr0 = vb + (size_t)( 0 + l15) * 1024 + e0;
      const uint16_t* vr1 = vb + (size_t)(16 + l15) * 1024 + e0;
      const uint16_t* vr2 = vb + (size_t)(32 + l15) * 1024 + e0;
      const uint16_t* vr3 = vb + (size_t)(48 + l15) * 1024 + e0;
      bf16x8 va;
      va = *(const bf16x8*)(vr0);      o0 = __builtin_amdgcn_mfma_f32_16x16x32_bf16(va, pb0, o0, 0,0,0);
      va = *(const bf16x8*)(vr0 + 32); o0 = __builtin_amdgcn_mfma_f32_16x16x32_bf16(va, pb1, o0, 0,0,0);
      va = *(const bf16x8*)(vr1);      o1 = __builtin_amdgcn_mfma_f32_16x16x32_bf16(va, pb0, o1, 0,0,0);
      va = *(const bf16x8*)(vr1 + 32); o1 = __builtin_amdgcn_mfma_f32_16x16x32_bf16(va, pb1, o1, 0,0,0);
      va = *(const bf16x8*)(vr2);      o2 = __builtin_amdgcn_mfma_f32_16x16x32_bf16(va, pb0, o2, 0,0,0);
      va = *(const bf16x8*)(vr2 + 32); o2 = __builtin_amdgcn_mfma_f32_16x16x32_bf16(va, pb1, o2, 0,0,0);
      va = *(const bf16x8*)(vr3);      o3 = __builtin_amdgcn_mfma_f32_16x16x32_bf16(va, pb0, o3, 0,0,0);
      va = *(const bf16x8*)(vr3 + 32); o3 = __builtin_amdgcn_mfma_f32_16x16x32_bf16(va, pb1, o3, 0,0,0);
    }
  }

  // ---- store partial O^T (unnormalized) + per-c m,l ----
  float* po = wsf + PART_O_F + (size_t)bid * 1024;
  *(f32x4*)&po[0 * 256 + l * 4] = o0;
  *(f32x4*)&po[1 * 256 + l * 4] = o1;
  *(f32x4*)&po[2 * 256 + l * 4] = o2;
  *(f32x4*)&po[3 * 256 + l * 4] = o3;
  if (lg == 0) {
    wsf[PART_ML_F + (size_t)bid * 32 + l15]      = mrun;
    wsf[PART_ML_F + (size_t)bid * 32 + 16 + l15] = lrun;
  }
}

// K4: merge 4 e-chunk partials per (bn, c-tile): max-rebase, combine, normalize.
// grid 512 = 8 bn x 64 c-tiles, block 64.
__global__ __launch_bounds__(64) void k4_merge(
    const float* __restrict__ wsf, float* __restrict__ out) {
  const int l = threadIdx.x;
  const int l15 = l & 15, lg = l >> 4;
  const int bn = blockIdx.x >> 6, ct = blockIdx.x & 63;
  const size_t t0 = (size_t)blockIdx.x * 4;

  const float* mlb = wsf + PART_ML_F + t0 * 32;
  float m0 = mlb[0 * 32 + l15], l0 = mlb[0 * 32 + 16 + l15];
  float m1 = mlb[1 * 32 + l15], l1 = mlb[1 * 32 + 16 + l15];
  float m2 = mlb[2 * 32 + l15], l2 = mlb[2 * 32 + 16 + l15];
  float m3 = mlb[3 * 32 + l15], l3 = mlb[3 * 32 + 16 + l15];
  const float M = fmaxf(fmaxf(m0, m1), fmaxf(m2, m3));
  const float c0 = __expf(m0 - M), c1 = __expf(m1 - M);
  const float c2 = __expf(m2 - M), c3 = __expf(m3 - M);
  const float L = c0 * l0 + c1 * l1 + c2 * l2 + c3 * l3;
  const float rl = __builtin_amdgcn_rcpf(L);

  const float* pb = wsf + PART_O_F + t0 * 1024;
  f32x4 a0 = {0.f,0.f,0.f,0.f}, a1 = a0, a2 = a0, a3 = a0;
  #pragma unroll
  for (int j = 0; j < 4; ++j) {
    const float cj = (j == 0) ? c0 : (j == 1) ? c1 : (j == 2) ? c2 : c3;
    const f32x4 p0 = *(const f32x4*)&pb[j * 1024 + 0 * 256 + l * 4];
    const f32x4 p1 = *(const f32x4*)&pb[j * 1024 + 1 * 256 + l * 4];
    const f32x4 p2 = *(const f32x4*)&pb[j * 1024 + 2 * 256 + l * 4];
    const f32x4 p3 = *(const f32x4*)&pb[j * 1024 + 3 * 256 + l * 4];
    #pragma unroll
    for (int p = 0; p < 4; ++p) {
      a0[p] += cj * p0[p]; a1[p] += cj * p1[p];
      a2[p] += cj * p2[p]; a3[p] += cj * p3[p];
    }
  }

  const int C = ct * 16 + l15;
  float* ob = out + ((size_t)bn * 256 + (C >> 2)) * 256 + (C & 3) * 64;
  #pragma unroll
  for (int p = 0; p < 4; ++p) {
    ob[ 0 + lg * 4 + p] = a0[p] * rl;
    ob[16 + lg * 4 + p] = a1[p] * rl;
    ob[32 + lg * 4 + p] = a2[p] * rl;
    ob[48 + lg * 4 + p] = a3[p] * rl;
  }
}

extern "C" void kernel_launch(void* const* d_in, const int* in_sizes, int n_in,
                              void* d_out, int out_size, void* d_ws, size_t ws_size,
                              hipStream_t stream) {
  (void)in_sizes; (void)n_in; (void)out_size; (void)ws_size;
  const float* x      = (const float*)d_in[0];
  const float* conv_w = (const float*)d_in[1];
  const float* conv_b = (const float*)d_in[2];
  const float* qW1 = (const float*)d_in[3];
  const float* qb1 = (const float*)d_in[4];
  const float* qW2 = (const float*)d_in[5];
  const float* qb2 = (const float*)d_in[6];
  const float* kW1 = (const float*)d_in[7];
  const float* kb1 = (const float*)d_in[8];
  const float* kW2 = (const float*)d_in[9];
  const float* kb2 = (const float*)d_in[10];
  const float* vW1 = (const float*)d_in[11];
  const float* vb1 = (const float*)d_in[12];
  const float* vW2 = (const float*)d_in[13];
  const float* vb2 = (const float*)d_in[14];
  const float* temp = (const float*)d_in[15];
  float* wsf = (float*)d_ws;
  uint16_t* wsu = (uint16_t*)(wsf + U16_BASE_F);
  float* out = (float*)d_out;

  k1_G<<<dim3(1606), dim3(64), 0, stream>>>(x, qW1, kW1, vW1,
      conv_w, qW2, kW2, vW2, wsf, wsu);
  k2_mfma<<<dim3(1536), dim3(256), 0, stream>>>(
      wsu + GP_U, wsu + CW_U, wsu + W2T_U, conv_b,
      qb1, kb1, vb1, qb2, kb2, vb2, wsf, wsu);
  k3_attn<<<dim3(2048), dim3(64), 0, stream>>>(
      wsu + QU_O, wsu + KU_O, wsu + VT_O, temp, wsf);
  k4_merge<<<dim3(512), dim3(64), 0, stream>>>(wsf, out);
}

// Round 9
// 53.845 us; speedup vs baseline: 3.3347x; 1.0014x over previous
//
#include <hip/hip_runtime.h>
#include <cstdint>

constexpr int NB  = 2;     // batch
constexpr int NCI = 4;     // conv input channels
constexpr int NHH = 256;   // H
constexpr int NWW = 256;   // W
constexpr int NCT = 1024;  // conv output channels

// ---------------- workspace layout ----------------
// float region: W1 column sums, then (after u16 region) attention partials
constexpr size_t SW1F = 0;            // 48 floats
constexpr size_t U16_BASE_F = 48;     // u16 region starts here
// u16 offsets (relative to wsu):
constexpr size_t GP_U  = 0;           // G'bf [m][b][i][dx][r][258]
constexpr size_t CW_U  = 297216;      // CW_bf [o][40]
constexpr size_t W2T_U = 338176;      // W2T_bf [m][s][h]
constexpr size_t QU_O  = 350464;      // Q  bf16 [bn][o][xsp]
constexpr size_t KU_O  = 874752;      // K  bf16 [bn][o][xsp]
constexpr size_t VT_O  = 1399040;     // V^T bf16 [bn][xsp][o]
// u16 region ends at 1923328 u16 = 961664 floats
constexpr size_t PART_O_F  = 961712;              // 2048 tasks x 1024 f32
constexpr size_t PART_ML_F = PART_O_F + 2097152;  // 2048 tasks x (16 m + 16 l)

typedef __attribute__((ext_vector_type(8))) short bf16x8;
typedef __attribute__((ext_vector_type(4))) float f32x4;

__device__ __forceinline__ uint16_t f2bf(float x) {
  uint32_t u = __float_as_uint(x);
  return (uint16_t)((u + 0x7FFFu + ((u >> 16) & 1u)) >> 16);   // RNE
}
__device__ __forceinline__ uint32_t pk2bf(float a, float b) {  // lo=bf(a), hi=bf(b)
  const uint32_t au = __float_as_uint(a) + 0x8000u;
  const uint32_t bu = __float_as_uint(b) + 0x8000u;
  return __builtin_amdgcn_perm(bu, au, 0x07060302u);
}
__device__ __forceinline__ float sigmoid_f(float v) {
  return __builtin_amdgcn_rcpf(1.0f + __expf(-v));
}

// K1: G'bf[m][b][i][dx][r][1+h] = bf16( sum_w x_pad[b,i,h,w+dx-1] * W1_m[w,r] )
// plus sw1 sums, plus CW_bf / W2T_bf prep blocks.  (unchanged)
__global__ __launch_bounds__(64) void k1_G(
    const float* __restrict__ x,
    const float* __restrict__ qW1, const float* __restrict__ kW1,
    const float* __restrict__ vW1,
    const float* __restrict__ conv_w,
    const float* __restrict__ qW2, const float* __restrict__ kW2,
    const float* __restrict__ vW2,
    float* __restrict__ wsf, uint16_t* __restrict__ wsu) {
  const int tid = threadIdx.x;
  const int NBLK = 3 * NB * NCI * (NHH / 4);   // 1536
  int bid = blockIdx.x;

  if (bid >= NBLK + 3 + 64) {                  // W2T_bf prep (3 blocks)
    const int m = bid - (NBLK + 3 + 64);
    const float* W2 = (m == 0) ? qW2 : (m == 1) ? kW2 : vW2;
    for (int u = 0; u < 64; ++u) {
      const int idx = tid * 64 + u;            // 4096 = 16 s x 256 h
      const int s = idx >> 8, h = idx & 255;
      wsu[W2T_U + (size_t)m * 4096 + s * 256 + h] = f2bf(W2[h * 16 + s]);
    }
    return;
  }
  if (bid >= NBLK + 3) {                       // CW_bf prep (64 blocks x 16 o)
    const int p = bid - (NBLK + 3);
    const int o = p * 16 + (tid >> 2);
    const int ks = (tid & 3) * 10;
    for (int u = 0; u < 10; ++u) {
      const int k = ks + u;
      wsu[CW_U + (size_t)o * 40 + k] = (k < 36) ? f2bf(conv_w[o * 36 + k]) : (uint16_t)0;
    }
    return;
  }
  if (bid >= NBLK) {                           // sw1 column sums
    int m = bid - NBLK;
    if (tid < 16) {
      const float* W1 = (m == 0) ? qW1 : (m == 1) ? kW1 : vW1;
      float s = 0.f;
      for (int w = 0; w < 256; ++w) s += W1[w * 16 + tid];
      wsf[SW1F + m * 16 + tid] = s;
    }
    return;
  }

  const int m  = bid / (NB * NCI * (NHH / 4));
  int rem      = bid % (NB * NCI * (NHH / 4));
  const int b  = rem / (NCI * (NHH / 4));
  rem          = rem % (NCI * (NHH / 4));
  const int i  = rem / (NHH / 4);
  const int h0 = (rem % (NHH / 4)) * 4;
  const int mb = m * NB + b;

  const float* W1 = (m == 0) ? qW1 : (m == 1) ? kW1 : vW1;

  __shared__ float W1l[16 * 260];
  __shared__ float xlb[4][260];

  for (int idx4 = tid; idx4 < 1024; idx4 += 64) {
    const float4 t = ((const float4*)W1)[idx4];
    const int w = idx4 >> 2, r0 = (idx4 & 3) * 4;
    W1l[(r0 + 0) * 260 + w] = t.x;
    W1l[(r0 + 1) * 260 + w] = t.y;
    W1l[(r0 + 2) * 260 + w] = t.z;
    W1l[(r0 + 3) * 260 + w] = t.w;
  }
  const float* xbase = x + ((size_t)(b * NCI + i) * NHH + h0) * NWW;
  for (int idx = tid; idx < 4 * 256; idx += 64) {
    const int rr = idx >> 8, w = idx & 255;
    xlb[rr][1 + w] = xbase[rr * NWW + w];
  }
  if (tid < 4) {
    xlb[tid][0] = 0.f; xlb[tid][257] = 0.f; xlb[tid][258] = 0.f; xlb[tid][259] = 0.f;
  }
  __syncthreads();

  // pad rows hp=0 and hp=257 (zeros)
  if (h0 == 0 && tid < 48) {
    const int dxp = tid >> 4, rp = tid & 15;
    wsu[GP_U + ((size_t)((mb * 4 + i) * 3 + dxp) * 16 + rp) * 258 + 0] = 0;
  }
  if (h0 == 252 && tid < 48) {
    const int dxp = tid >> 4, rp = tid & 15;
    wsu[GP_U + ((size_t)((mb * 4 + i) * 3 + dxp) * 16 + rp) * 258 + 257] = 0;
  }

  const int wc = tid >> 4, r = tid & 15;
  const int w0 = wc * 64;
  const size_t gb0 = GP_U + ((size_t)((mb * 4 + i) * 3 + 0) * 16 + r) * 258;

  #pragma unroll
  for (int rr = 0; rr < 4; ++rr) {
    const float* xl = xlb[rr];
    float a0 = 0.f, a1 = 0.f, a2 = 0.f;
    float4 cur = *(const float4*)&xl[w0];
    #pragma unroll 4
    for (int w = w0; w < w0 + 64; w += 4) {
      const float4 nxt = *(const float4*)&xl[w + 4];
      const float4 w1  = *(const float4*)&W1l[r * 260 + w];
      a0 += w1.x * cur.x + w1.y * cur.y + w1.z * cur.z + w1.w * cur.w;
      a1 += w1.x * cur.y + w1.y * cur.z + w1.z * cur.w + w1.w * nxt.x;
      a2 += w1.x * cur.z + w1.y * cur.w + w1.z * nxt.x + w1.w * nxt.y;
      cur = nxt;
    }
    a0 += __shfl_xor(a0, 16, 64); a0 += __shfl_xor(a0, 32, 64);
    a1 += __shfl_xor(a1, 16, 64); a1 += __shfl_xor(a1, 32, 64);
    a2 += __shfl_xor(a2, 16, 64); a2 += __shfl_xor(a2, 32, 64);
    if (wc == 0) {
      const int hp = 1 + h0 + rr;
      wsu[gb0 + hp]        = f2bf(a0);   // dx = 0
      wsu[gb0 + 4128 + hp] = f2bf(a1);   // dx = 1
      wsu[gb0 + 8256 + hp] = f2bf(a2);   // dx = 2
    }
  }
}

// K2 (MFMA): bf16 epilogue: Q,K [bn][o][xsp], V^T [bn][xsp][o].  (unchanged)
__global__ __launch_bounds__(256, 4) void k2_mfma(
    const uint16_t* __restrict__ gp, const uint16_t* __restrict__ cwbf,
    const uint16_t* __restrict__ w2t,
    const float* __restrict__ conv_b,
    const float* __restrict__ qb1, const float* __restrict__ kb1, const float* __restrict__ vb1,
    const float* __restrict__ qb2, const float* __restrict__ kb2, const float* __restrict__ vb2,
    const float* __restrict__ wsf, uint16_t* __restrict__ wsu) {
  const int tid = threadIdx.x;
  const int bid = blockIdx.x;
  const int r  = bid & 15;
  const int og = (bid >> 4) & 15;
  const int mb = bid >> 8;            // 0..5
  const int m  = mb >> 1, b = mb & 1;

  const int wv  = tid >> 6;
  const int l   = tid & 63;
  const int l15 = l & 15;
  const int lg  = l >> 4;

  __shared__ uint16_t GS[256 * 40];     // [h][k]
  __shared__ uint16_t y1l[4][16 * 72];  // per-wave [o16][h64+8pad]

  {
    const int h = tid;
    uint16_t* gsrow = &GS[h * 40];
    #pragma unroll
    for (int i = 0; i < 4; ++i) {
      #pragma unroll
      for (int dx = 0; dx < 3; ++dx) {
        const uint16_t* g = gp + ((size_t)((mb * 4 + i) * 3 + dx) * 16 + r) * 258 + h;
        gsrow[i * 9 + 0 * 3 + dx] = g[0];
        gsrow[i * 9 + 1 * 3 + dx] = g[1];
        gsrow[i * 9 + 2 * 3 + dx] = g[2];
      }
    }
    gsrow[36] = 0; gsrow[37] = 0; gsrow[38] = 0; gsrow[39] = 0;
  }
  __syncthreads();

  const float* b1 = (m == 0) ? qb1 : (m == 1) ? kb1 : vb1;
  const float* b2 = (m == 0) ? qb2 : (m == 1) ? kb2 : vb2;

  const int o_blk = og * 64 + wv * 16;

  const uint16_t* cwrow = cwbf + (size_t)(o_blk + l15) * 40;
  bf16x8 cw0 = *(const bf16x8*)(cwrow + lg * 8);
  bf16x8 cw1 = {0,0,0,0,0,0,0,0};
  if (lg == 0) cw1 = *(const bf16x8*)(cwrow + 32);

  const uint16_t* w2row = w2t + (size_t)m * 4096 + (size_t)l15 * 256 + lg * 8;
  bf16x8 w2f0 = *(const bf16x8*)(w2row + 0 * 32);
  bf16x8 w2f1 = *(const bf16x8*)(w2row + 1 * 32);
  bf16x8 w2f2 = *(const bf16x8*)(w2row + 2 * 32);
  bf16x8 w2f3 = *(const bf16x8*)(w2row + 3 * 32);
  bf16x8 w2f4 = *(const bf16x8*)(w2row + 4 * 32);
  bf16x8 w2f5 = *(const bf16x8*)(w2row + 5 * 32);
  bf16x8 w2f6 = *(const bf16x8*)(w2row + 6 * 32);
  bf16x8 w2f7 = *(const bf16x8*)(w2row + 7 * 32);

  const float sw1r = wsf[SW1F + m * 16 + r];
  const float b1r  = b1[r];
  const float cbv  = conv_b[o_blk + l15];
  const float bias1 = cbv * sw1r + b1r;
  const float b2v  = b2[l15];

  uint16_t* yw = &y1l[wv][0];
  f32x4 acc2 = {0.f, 0.f, 0.f, 0.f};

  #pragma unroll
  for (int cc = 0; cc < 4; ++cc) {
    #pragma unroll
    for (int ct = 0; ct < 4; ++ct) {
      const uint16_t* arow = &GS[(cc * 64 + ct * 16 + l15) * 40];
      bf16x8 a0 = *(const bf16x8*)(arow + lg * 8);
      bf16x8 a1 = {0,0,0,0,0,0,0,0};
      if (lg == 0) a1 = *(const bf16x8*)(arow + 32);
      f32x4 d = {0.f, 0.f, 0.f, 0.f};
      d = __builtin_amdgcn_mfma_f32_16x16x32_bf16(a0, cw0, d, 0, 0, 0);
      d = __builtin_amdgcn_mfma_f32_16x16x32_bf16(a1, cw1, d, 0, 0, 0);
      const float y0 = sigmoid_f(d[0] + bias1);
      const float y1 = sigmoid_f(d[1] + bias1);
      const float y2 = sigmoid_f(d[2] + bias1);
      const float y3 = sigmoid_f(d[3] + bias1);
      uint32_t* yd = (uint32_t*)&yw[l15 * 72 + ct * 16 + lg * 4];
      yd[0] = pk2bf(y0, y1);
      yd[1] = pk2bf(y2, y3);
    }
    {
      const uint16_t* yrow = &yw[l15 * 72 + lg * 8];
      bf16x8 ya0 = *(const bf16x8*)(yrow + 0);
      bf16x8 ya1 = *(const bf16x8*)(yrow + 32);
      if (cc == 0) {
        acc2 = __builtin_amdgcn_mfma_f32_16x16x32_bf16(ya0, w2f0, acc2, 0, 0, 0);
        acc2 = __builtin_amdgcn_mfma_f32_16x16x32_bf16(ya1, w2f1, acc2, 0, 0, 0);
      } else if (cc == 1) {
        acc2 = __builtin_amdgcn_mfma_f32_16x16x32_bf16(ya0, w2f2, acc2, 0, 0, 0);
        acc2 = __builtin_amdgcn_mfma_f32_16x16x32_bf16(ya1, w2f3, acc2, 0, 0, 0);
      } else if (cc == 2) {
        acc2 = __builtin_amdgcn_mfma_f32_16x16x32_bf16(ya0, w2f4, acc2, 0, 0, 0);
        acc2 = __builtin_amdgcn_mfma_f32_16x16x32_bf16(ya1, w2f5, acc2, 0, 0, 0);
      } else {
        acc2 = __builtin_amdgcn_mfma_f32_16x16x32_bf16(ya0, w2f6, acc2, 0, 0, 0);
        acc2 = __builtin_amdgcn_mfma_f32_16x16x32_bf16(ya1, w2f7, acc2, 0, 0, 0);
      }
    }
  }

  // epilogue: y2 = sigmoid(acc2 + b2) -> bf16 q/k/vT
  const int s   = l15;
  const int n   = (s & 1) * 2 + (r & 1);
  const int xsp = (s >> 1) * 8 + (r >> 1);
  const int bn  = b * 4 + n;
  uint16_t* qk = wsu + ((m == 0) ? QU_O : KU_O);
  uint16_t* vT = wsu + VT_O;
  #pragma unroll
  for (int p = 0; p < 4; ++p) {
    const int o = o_blk + lg * 4 + p;
    const uint16_t y2 = f2bf(sigmoid_f(acc2[p] + b2v));
    if (m == 2) vT[((size_t)bn * 64 + xsp) * 1024 + o] = y2;
    else        qk[((size_t)bn * 1024 + o) * 64 + xsp] = y2;
  }
}

// K3 (split-KV flash): grid 2048 = 8 bn x 64 c-tiles x 4 e-chunks, block 64.
// Per 64-e tile: S^T = mfma(K, Q) -> online softmax -> P bf16 (wave LDS) ->
// O^T += mfma(V^T, P). Writes unnormalized partial O^T + (m, l) per task.
__global__ __launch_bounds__(64) void k3_attn(
    const uint16_t* __restrict__ qu, const uint16_t* __restrict__ ku,
    const uint16_t* __restrict__ vtu, const float* __restrict__ temp,
    float* __restrict__ wsf) {
  const int l   = threadIdx.x;
  const int l15 = l & 15, lg = l >> 4;
  const int bid = blockIdx.x;
  const int bn = bid >> 8;
  const int ct = (bid >> 2) & 63;
  const int ec = bid & 3;
  const int cbase = ct * 16;
  const float tscale = temp[bn & 3];

  __shared__ uint16_t P_lds[2][16 * 72];   // [c][64 e + 8 pad], double-buffered

  // Q B-frags: B[k=d][col=c] from Q[bn][c][d]
  const uint16_t* qrow = qu + (size_t)(bn * 1024 + cbase + l15) * 64 + lg * 8;
  const bf16x8 qf0 = *(const bf16x8*)(qrow);
  const bf16x8 qf1 = *(const bf16x8*)(qrow + 32);

  const uint16_t* kb = ku  + (size_t)bn * 65536 + lg * 8;
  const uint16_t* vb = vtu + (size_t)bn * 65536 + lg * 8;

  f32x4 o0 = {0.f,0.f,0.f,0.f}, o1 = o0, o2 = o0, o3 = o0;  // O^T[x][c], 4 x-tiles
  float mrun = -3.0e38f, lrun = 0.f;

  #pragma unroll
  for (int et = 0; et < 4; ++et) {
    const int e0 = ec * 256 + et * 64;
    uint16_t* pl = &P_lds[et & 1][0];

    // ---- S^T tile: D[e][c] = sum_d K[e][d] Q[c][d], 4 e-subtiles ----
    f32x4 s0 = {0.f,0.f,0.f,0.f}, s1 = s0, s2 = s0, s3 = s0;
    {
      const uint16_t* kr0 = kb + (size_t)(e0 +  0 + l15) * 64;
      const uint16_t* kr1 = kb + (size_t)(e0 + 16 + l15) * 64;
      const uint16_t* kr2 = kb + (size_t)(e0 + 32 + l15) * 64;
      const uint16_t* kr3 = kb + (size_t)(e0 + 48 + l15) * 64;
      const bf16x8 ka0 = *(const bf16x8*)(kr0);
      const bf16x8 kb0 = *(const bf16x8*)(kr0 + 32);
      const bf16x8 ka1 = *(const bf16x8*)(kr1);
      const bf16x8 kb1_ = *(const bf16x8*)(kr1 + 32);
      const bf16x8 ka2 = *(const bf16x8*)(kr2);
      const bf16x8 kb2_ = *(const bf16x8*)(kr2 + 32);
      const bf16x8 ka3 = *(const bf16x8*)(kr3);
      const bf16x8 kb3_ = *(const bf16x8*)(kr3 + 32);
      s0 = __builtin_amdgcn_mfma_f32_16x16x32_bf16(ka0, qf0, s0, 0,0,0);
      s0 = __builtin_amdgcn_mfma_f32_16x16x32_bf16(kb0, qf1, s0, 0,0,0);
      s1 = __builtin_amdgcn_mfma_f32_16x16x32_bf16(ka1, qf0, s1, 0,0,0);
      s1 = __builtin_amdgcn_mfma_f32_16x16x32_bf16(kb1_, qf1, s1, 0,0,0);
      s2 = __builtin_amdgcn_mfma_f32_16x16x32_bf16(ka2, qf0, s2, 0,0,0);
      s2 = __builtin_amdgcn_mfma_f32_16x16x32_bf16(kb2_, qf1, s2, 0,0,0);
      s3 = __builtin_amdgcn_mfma_f32_16x16x32_bf16(ka3, qf0, s3, 0,0,0);
      s3 = __builtin_amdgcn_mfma_f32_16x16x32_bf16(kb3_, qf1, s3, 0,0,0);
    }
    #pragma unroll
    for (int p = 0; p < 4; ++p) {
      s0[p] *= tscale; s1[p] *= tscale; s2[p] *= tscale; s3[p] *= tscale;
    }

    // ---- online softmax per c (col = l15) ----
    float t0 = fmaxf(fmaxf(s0[0], s0[1]), fmaxf(s0[2], s0[3]));
    float t1 = fmaxf(fmaxf(s1[0], s1[1]), fmaxf(s1[2], s1[3]));
    float t2 = fmaxf(fmaxf(s2[0], s2[1]), fmaxf(s2[2], s2[3]));
    float t3 = fmaxf(fmaxf(s3[0], s3[1]), fmaxf(s3[2], s3[3]));
    float tmax = fmaxf(fmaxf(t0, t1), fmaxf(t2, t3));
    tmax = fmaxf(tmax, __shfl_xor(tmax, 16, 64));
    tmax = fmaxf(tmax, __shfl_xor(tmax, 32, 64));
    const float mnew = fmaxf(mrun, tmax);
    const float scl  = __expf(mrun - mnew);
    float psum = 0.f;
    #pragma unroll
    for (int p = 0; p < 4; ++p) { s0[p] = __expf(s0[p] - mnew); psum += s0[p]; }
    #pragma unroll
    for (int p = 0; p < 4; ++p) { s1[p] = __expf(s1[p] - mnew); psum += s1[p]; }
    #pragma unroll
    for (int p = 0; p < 4; ++p) { s2[p] = __expf(s2[p] - mnew); psum += s2[p]; }
    #pragma unroll
    for (int p = 0; p < 4; ++p) { s3[p] = __expf(s3[p] - mnew); psum += s3[p]; }
    psum += __shfl_xor(psum, 16, 64);
    psum += __shfl_xor(psum, 32, 64);
    lrun = lrun * scl + psum;
    mrun = mnew;

    // ---- pack P -> LDS [c][e] ----
    {
      uint32_t* p0w = (uint32_t*)&pl[l15 * 72 +  0 + lg * 4];
      uint32_t* p1w = (uint32_t*)&pl[l15 * 72 + 16 + lg * 4];
      uint32_t* p2w = (uint32_t*)&pl[l15 * 72 + 32 + lg * 4];
      uint32_t* p3w = (uint32_t*)&pl[l15 * 72 + 48 + lg * 4];
      p0w[0] = pk2bf(s0[0], s0[1]); p0w[1] = pk2bf(s0[2], s0[3]);
      p1w[0] = pk2bf(s1[0], s1[1]); p1w[1] = pk2bf(s1[2], s1[3]);
      p2w[0] = pk2bf(s2[0], s2[1]); p2w[1] = pk2bf(s2[2], s2[3]);
      p3w[0] = pk2bf(s3[0], s3[1]); p3w[1] = pk2bf(s3[2], s3[3]);
    }

    // ---- rescale O^T by scl (per-c = lane-local) ----
    #pragma unroll
    for (int p = 0; p < 4; ++p) {
      o0[p] *= scl; o1[p] *= scl; o2[p] *= scl; o3[p] *= scl;
    }

    // ---- PV: O^T[x][c] += sum_e V^T[x][e] P[e][c] ----
    {
      const bf16x8 pb0 = *(const bf16x8*)&pl[l15 * 72 +  0 + lg * 8];
      const bf16x8 pb1 = *(const bf16x8*)&pl[l15 * 72 + 32 + lg * 8];
      const uint16_t* vr0 = vb + (size_t)( 0 + l15) * 1024 + e0;
      const uint16_t* vr1 = vb + (size_t)(16 + l15) * 1024 + e0;
      const uint16_t* vr2 = vb + (size_t)(32 + l15) * 1024 + e0;
      const uint16_t* vr3 = vb + (size_t)(48 + l15) * 1024 + e0;
      bf16x8 va;
      va = *(const bf16x8*)(vr0);      o0 = __builtin_amdgcn_mfma_f32_16x16x32_bf16(va, pb0, o0, 0,0,0);
      va = *(const bf16x8*)(vr0 + 32); o0 = __builtin_amdgcn_mfma_f32_16x16x32_bf16(va, pb1, o0, 0,0,0);
      va = *(const bf16x8*)(vr1);      o1 = __builtin_amdgcn_mfma_f32_16x16x32_bf16(va, pb0, o1, 0,0,0);
      va = *(const bf16x8*)(vr1 + 32); o1 = __builtin_amdgcn_mfma_f32_16x16x32_bf16(va, pb1, o1, 0,0,0);
      va = *(const bf16x8*)(vr2);      o2 = __builtin_amdgcn_mfma_f32_16x16x32_bf16(va, pb0, o2, 0,0,0);
      va = *(const bf16x8*)(vr2 + 32); o2 = __builtin_amdgcn_mfma_f32_16x16x32_bf16(va, pb1, o2, 0,0,0);
      va = *(const bf16x8*)(vr3);      o3 = __builtin_amdgcn_mfma_f32_16x16x32_bf16(va, pb0, o3, 0,0,0);
      va = *(const bf16x8*)(vr3 + 32); o3 = __builtin_amdgcn_mfma_f32_16x16x32_bf16(va, pb1, o3, 0,0,0);
    }
  }

  // ---- store partial O^T (unnormalized) + per-c m,l ----
  float* po = wsf + PART_O_F + (size_t)bid * 1024;
  *(f32x4*)&po[0 * 256 + l * 4] = o0;
  *(f32x4*)&po[1 * 256 + l * 4] = o1;
  *(f32x4*)&po[2 * 256 + l * 4] = o2;
  *(f32x4*)&po[3 * 256 + l * 4] = o3;
  if (lg == 0) {
    wsf[PART_ML_F + (size_t)bid * 32 + l15]      = mrun;
    wsf[PART_ML_F + (size_t)bid * 32 + 16 + l15] = lrun;
  }
}

// K4: merge 4 e-chunk partials per (bn, c-tile): max-rebase, combine, normalize.
// grid 512 = 8 bn x 64 c-tiles, block 64.
__global__ __launch_bounds__(64) void k4_merge(
    const float* __restrict__ wsf, float* __restrict__ out) {
  const int l = threadIdx.x;
  const int l15 = l & 15, lg = l >> 4;
  const int bn = blockIdx.x >> 6, ct = blockIdx.x & 63;
  const size_t t0 = (size_t)blockIdx.x * 4;

  const float* mlb = wsf + PART_ML_F + t0 * 32;
  float m0 = mlb[0 * 32 + l15], l0 = mlb[0 * 32 + 16 + l15];
  float m1 = mlb[1 * 32 + l15], l1 = mlb[1 * 32 + 16 + l15];
  float m2 = mlb[2 * 32 + l15], l2 = mlb[2 * 32 + 16 + l15];
  float m3 = mlb[3 * 32 + l15], l3 = mlb[3 * 32 + 16 + l15];
  const float M = fmaxf(fmaxf(m0, m1), fmaxf(m2, m3));
  const float c0 = __expf(m0 - M), c1 = __expf(m1 - M);
  const float c2 = __expf(m2 - M), c3 = __expf(m3 - M);
  const float L = c0 * l0 + c1 * l1 + c2 * l2 + c3 * l3;
  const float rl = __builtin_amdgcn_rcpf(L);

  const float* pb = wsf + PART_O_F + t0 * 1024;
  f32x4 a0 = {0.f,0.f,0.f,0.f}, a1 = a0, a2 = a0, a3 = a0;
  #pragma unroll
  for (int j = 0; j < 4; ++j) {
    const float cj = (j == 0) ? c0 : (j == 1) ? c1 : (j == 2) ? c2 : c3;
    const f32x4 p0 = *(const f32x4*)&pb[j * 1024 + 0 * 256 + l * 4];
    const f32x4 p1 = *(const f32x4*)&pb[j * 1024 + 1 * 256 + l * 4];
    const f32x4 p2 = *(const f32x4*)&pb[j * 1024 + 2 * 256 + l * 4];
    const f32x4 p3 = *(const f32x4*)&pb[j * 1024 + 3 * 256 + l * 4];
    #pragma unroll
    for (int p = 0; p < 4; ++p) {
      a0[p] += cj * p0[p]; a1[p] += cj * p1[p];
      a2[p] += cj * p2[p]; a3[p] += cj * p3[p];
    }
  }

  const int C = ct * 16 + l15;
  float* ob = out + ((size_t)bn * 256 + (C >> 2)) * 256 + (C & 3) * 64;
  #pragma unroll
  for (int p = 0; p < 4; ++p) {
    ob[ 0 + lg * 4 + p] = a0[p] * rl;
    ob[16 + lg * 4 + p] = a1[p] * rl;
    ob[32 + lg * 4 + p] = a2[p] * rl;
    ob[48 + lg * 4 + p] = a3[p] * rl;
  }
}

extern "C" void kernel_launch(void* const* d_in, const int* in_sizes, int n_in,
                              void* d_out, int out_size, void* d_ws, size_t ws_size,
                              hipStream_t stream) {
  (void)in_sizes; (void)n_in; (void)out_size; (void)ws_size;
  const float* x      = (const float*)d_in[0];
  const float* conv_w = (const float*)d_in[1];
  const float* conv_b = (const float*)d_in[2];
  const float* qW1 = (const float*)d_in[3];
  const float* qb1 = (const float*)d_in[4];
  const float* qW2 = (const float*)d_in[5];
  const float* qb2 = (const float*)d_in[6];
  const float* kW1 = (const float*)d_in[7];
  const float* kb1 = (const float*)d_in[8];
  const float* kW2 = (const float*)d_in[9];
  const float* kb2 = (const float*)d_in[10];
  const float* vW1 = (const float*)d_in[11];
  const float* vb1 = (const float*)d_in[12];
  const float* vW2 = (const float*)d_in[13];
  const float* vb2 = (const float*)d_in[14];
  const float* temp = (const float*)d_in[15];
  float* wsf = (float*)d_ws;
  uint16_t* wsu = (uint16_t*)(wsf + U16_BASE_F);
  float* out = (float*)d_out;

  k1_G<<<dim3(1606), dim3(64), 0, stream>>>(x, qW1, kW1, vW1,
      conv_w, qW2, kW2, vW2, wsf, wsu);
  k2_mfma<<<dim3(1536), dim3(256), 0, stream>>>(
      wsu + GP_U, wsu + CW_U, wsu + W2T_U, conv_b,
      qb1, kb1, vb1, qb2, kb2, vb2, wsf, wsu);
  k3_attn<<<dim3(2048), dim3(64), 0, stream>>>(
      wsu + QU_O, wsu + KU_O, wsu + VT_O, temp, wsf);
  k4_merge<<<dim3(512), dim3(64), 0, stream>>>(wsf, out);
}

// Round 10
// 49.068 us; speedup vs baseline: 3.6593x; 1.0973x over previous
//
#include <hip/hip_runtime.h>
#include <cstdint>

constexpr int NB  = 2;     // batch
constexpr int NCI = 4;     // conv input channels
constexpr int NHH = 256;   // H
constexpr int NWW = 256;   // W
constexpr int NCT = 1024;  // conv output channels

// ---------------- workspace layout ----------------
constexpr size_t SW1F = 0;            // 48 floats
constexpr size_t U16_BASE_F = 48;     // u16 region starts here
// u16 offsets (relative to wsu):
constexpr size_t GP_U  = 0;           // G'bf [m][b][i][dx][r][258]
constexpr size_t CW_U  = 297216;      // CW_bf [o][40]
constexpr size_t W2T_U = 338176;      // W2T_bf [m][s][h]
constexpr size_t QU_O  = 350464;      // Q  bf16 [bn][o][xsp]
constexpr size_t KU_O  = 874752;      // K  bf16 [bn][o][xsp]
constexpr size_t VT_O  = 1399040;     // V^T bf16 [bn][xsp][o]

typedef __attribute__((ext_vector_type(8))) short bf16x8;
typedef __attribute__((ext_vector_type(4))) float f32x4;

__device__ __forceinline__ uint16_t f2bf(float x) {
  uint32_t u = __float_as_uint(x);
  return (uint16_t)((u + 0x7FFFu + ((u >> 16) & 1u)) >> 16);   // RNE
}
__device__ __forceinline__ uint32_t pk2bf(float a, float b) {  // lo=bf(a), hi=bf(b)
  const uint32_t au = __float_as_uint(a) + 0x8000u;
  const uint32_t bu = __float_as_uint(b) + 0x8000u;
  return __builtin_amdgcn_perm(bu, au, 0x07060302u);
}
__device__ __forceinline__ float sigmoid_f(float v) {
  return __builtin_amdgcn_rcpf(1.0f + __expf(-v));
}

// K1: G'bf[m][b][i][dx][r][1+h] = bf16( sum_w x_pad[b,i,h,w+dx-1] * W1_m[w,r] )
// plus sw1 sums, plus CW_bf / W2T_bf prep blocks.  (unchanged)
__global__ __launch_bounds__(64) void k1_G(
    const float* __restrict__ x,
    const float* __restrict__ qW1, const float* __restrict__ kW1,
    const float* __restrict__ vW1,
    const float* __restrict__ conv_w,
    const float* __restrict__ qW2, const float* __restrict__ kW2,
    const float* __restrict__ vW2,
    float* __restrict__ wsf, uint16_t* __restrict__ wsu) {
  const int tid = threadIdx.x;
  const int NBLK = 3 * NB * NCI * (NHH / 4);   // 1536
  int bid = blockIdx.x;

  if (bid >= NBLK + 3 + 64) {                  // W2T_bf prep (3 blocks)
    const int m = bid - (NBLK + 3 + 64);
    const float* W2 = (m == 0) ? qW2 : (m == 1) ? kW2 : vW2;
    for (int u = 0; u < 64; ++u) {
      const int idx = tid * 64 + u;            // 4096 = 16 s x 256 h
      const int s = idx >> 8, h = idx & 255;
      wsu[W2T_U + (size_t)m * 4096 + s * 256 + h] = f2bf(W2[h * 16 + s]);
    }
    return;
  }
  if (bid >= NBLK + 3) {                       // CW_bf prep (64 blocks x 16 o)
    const int p = bid - (NBLK + 3);
    const int o = p * 16 + (tid >> 2);
    const int ks = (tid & 3) * 10;
    for (int u = 0; u < 10; ++u) {
      const int k = ks + u;
      wsu[CW_U + (size_t)o * 40 + k] = (k < 36) ? f2bf(conv_w[o * 36 + k]) : (uint16_t)0;
    }
    return;
  }
  if (bid >= NBLK) {                           // sw1 column sums
    int m = bid - NBLK;
    if (tid < 16) {
      const float* W1 = (m == 0) ? qW1 : (m == 1) ? kW1 : vW1;
      float s = 0.f;
      for (int w = 0; w < 256; ++w) s += W1[w * 16 + tid];
      wsf[SW1F + m * 16 + tid] = s;
    }
    return;
  }

  const int m  = bid / (NB * NCI * (NHH / 4));
  int rem      = bid % (NB * NCI * (NHH / 4));
  const int b  = rem / (NCI * (NHH / 4));
  rem          = rem % (NCI * (NHH / 4));
  const int i  = rem / (NHH / 4);
  const int h0 = (rem % (NHH / 4)) * 4;
  const int mb = m * NB + b;

  const float* W1 = (m == 0) ? qW1 : (m == 1) ? kW1 : vW1;

  __shared__ float W1l[16 * 260];
  __shared__ float xlb[4][260];

  for (int idx4 = tid; idx4 < 1024; idx4 += 64) {
    const float4 t = ((const float4*)W1)[idx4];
    const int w = idx4 >> 2, r0 = (idx4 & 3) * 4;
    W1l[(r0 + 0) * 260 + w] = t.x;
    W1l[(r0 + 1) * 260 + w] = t.y;
    W1l[(r0 + 2) * 260 + w] = t.z;
    W1l[(r0 + 3) * 260 + w] = t.w;
  }
  const float* xbase = x + ((size_t)(b * NCI + i) * NHH + h0) * NWW;
  for (int idx = tid; idx < 4 * 256; idx += 64) {
    const int rr = idx >> 8, w = idx & 255;
    xlb[rr][1 + w] = xbase[rr * NWW + w];
  }
  if (tid < 4) {
    xlb[tid][0] = 0.f; xlb[tid][257] = 0.f; xlb[tid][258] = 0.f; xlb[tid][259] = 0.f;
  }
  __syncthreads();

  // pad rows hp=0 and hp=257 (zeros)
  if (h0 == 0 && tid < 48) {
    const int dxp = tid >> 4, rp = tid & 15;
    wsu[GP_U + ((size_t)((mb * 4 + i) * 3 + dxp) * 16 + rp) * 258 + 0] = 0;
  }
  if (h0 == 252 && tid < 48) {
    const int dxp = tid >> 4, rp = tid & 15;
    wsu[GP_U + ((size_t)((mb * 4 + i) * 3 + dxp) * 16 + rp) * 258 + 257] = 0;
  }

  const int wc = tid >> 4, r = tid & 15;
  const int w0 = wc * 64;
  const size_t gb0 = GP_U + ((size_t)((mb * 4 + i) * 3 + 0) * 16 + r) * 258;

  #pragma unroll
  for (int rr = 0; rr < 4; ++rr) {
    const float* xl = xlb[rr];
    float a0 = 0.f, a1 = 0.f, a2 = 0.f;
    float4 cur = *(const float4*)&xl[w0];
    #pragma unroll 4
    for (int w = w0; w < w0 + 64; w += 4) {
      const float4 nxt = *(const float4*)&xl[w + 4];
      const float4 w1  = *(const float4*)&W1l[r * 260 + w];
      a0 += w1.x * cur.x + w1.y * cur.y + w1.z * cur.z + w1.w * cur.w;
      a1 += w1.x * cur.y + w1.y * cur.z + w1.z * cur.w + w1.w * nxt.x;
      a2 += w1.x * cur.z + w1.y * cur.w + w1.z * nxt.x + w1.w * nxt.y;
      cur = nxt;
    }
    a0 += __shfl_xor(a0, 16, 64); a0 += __shfl_xor(a0, 32, 64);
    a1 += __shfl_xor(a1, 16, 64); a1 += __shfl_xor(a1, 32, 64);
    a2 += __shfl_xor(a2, 16, 64); a2 += __shfl_xor(a2, 32, 64);
    if (wc == 0) {
      const int hp = 1 + h0 + rr;
      wsu[gb0 + hp]        = f2bf(a0);   // dx = 0
      wsu[gb0 + 4128 + hp] = f2bf(a1);   // dx = 1
      wsu[gb0 + 8256 + hp] = f2bf(a2);   // dx = 2
    }
  }
}

// K2 (MFMA): bf16 epilogue: Q,K [bn][o][xsp], V^T [bn][xsp][o].  (unchanged)
__global__ __launch_bounds__(256, 4) void k2_mfma(
    const uint16_t* __restrict__ gp, const uint16_t* __restrict__ cwbf,
    const uint16_t* __restrict__ w2t,
    const float* __restrict__ conv_b,
    const float* __restrict__ qb1, const float* __restrict__ kb1, const float* __restrict__ vb1,
    const float* __restrict__ qb2, const float* __restrict__ kb2, const float* __restrict__ vb2,
    const float* __restrict__ wsf, uint16_t* __restrict__ wsu) {
  const int tid = threadIdx.x;
  const int bid = blockIdx.x;
  const int r  = bid & 15;
  const int og = (bid >> 4) & 15;
  const int mb = bid >> 8;            // 0..5
  const int m  = mb >> 1, b = mb & 1;

  const int wv  = tid >> 6;
  const int l   = tid & 63;
  const int l15 = l & 15;
  const int lg  = l >> 4;

  __shared__ uint16_t GS[256 * 40];     // [h][k]
  __shared__ uint16_t y1l[4][16 * 72];  // per-wave [o16][h64+8pad]

  {
    const int h = tid;
    uint16_t* gsrow = &GS[h * 40];
    #pragma unroll
    for (int i = 0; i < 4; ++i) {
      #pragma unroll
      for (int dx = 0; dx < 3; ++dx) {
        const uint16_t* g = gp + ((size_t)((mb * 4 + i) * 3 + dx) * 16 + r) * 258 + h;
        gsrow[i * 9 + 0 * 3 + dx] = g[0];
        gsrow[i * 9 + 1 * 3 + dx] = g[1];
        gsrow[i * 9 + 2 * 3 + dx] = g[2];
      }
    }
    gsrow[36] = 0; gsrow[37] = 0; gsrow[38] = 0; gsrow[39] = 0;
  }
  __syncthreads();

  const float* b1 = (m == 0) ? qb1 : (m == 1) ? kb1 : vb1;
  const float* b2 = (m == 0) ? qb2 : (m == 1) ? kb2 : vb2;

  const int o_blk = og * 64 + wv * 16;

  const uint16_t* cwrow = cwbf + (size_t)(o_blk + l15) * 40;
  bf16x8 cw0 = *(const bf16x8*)(cwrow + lg * 8);
  bf16x8 cw1 = {0,0,0,0,0,0,0,0};
  if (lg == 0) cw1 = *(const bf16x8*)(cwrow + 32);

  const uint16_t* w2row = w2t + (size_t)m * 4096 + (size_t)l15 * 256 + lg * 8;
  bf16x8 w2f0 = *(const bf16x8*)(w2row + 0 * 32);
  bf16x8 w2f1 = *(const bf16x8*)(w2row + 1 * 32);
  bf16x8 w2f2 = *(const bf16x8*)(w2row + 2 * 32);
  bf16x8 w2f3 = *(const bf16x8*)(w2row + 3 * 32);
  bf16x8 w2f4 = *(const bf16x8*)(w2row + 4 * 32);
  bf16x8 w2f5 = *(const bf16x8*)(w2row + 5 * 32);
  bf16x8 w2f6 = *(const bf16x8*)(w2row + 6 * 32);
  bf16x8 w2f7 = *(const bf16x8*)(w2row + 7 * 32);

  const float sw1r = wsf[SW1F + m * 16 + r];
  const float b1r  = b1[r];
  const float cbv  = conv_b[o_blk + l15];
  const float bias1 = cbv * sw1r + b1r;
  const float b2v  = b2[l15];

  uint16_t* yw = &y1l[wv][0];
  f32x4 acc2 = {0.f, 0.f, 0.f, 0.f};

  #pragma unroll
  for (int cc = 0; cc < 4; ++cc) {
    #pragma unroll
    for (int ct = 0; ct < 4; ++ct) {
      const uint16_t* arow = &GS[(cc * 64 + ct * 16 + l15) * 40];
      bf16x8 a0 = *(const bf16x8*)(arow + lg * 8);
      bf16x8 a1 = {0,0,0,0,0,0,0,0};
      if (lg == 0) a1 = *(const bf16x8*)(arow + 32);
      f32x4 d = {0.f, 0.f, 0.f, 0.f};
      d = __builtin_amdgcn_mfma_f32_16x16x32_bf16(a0, cw0, d, 0, 0, 0);
      d = __builtin_amdgcn_mfma_f32_16x16x32_bf16(a1, cw1, d, 0, 0, 0);
      const float y0 = sigmoid_f(d[0] + bias1);
      const float y1 = sigmoid_f(d[1] + bias1);
      const float y2 = sigmoid_f(d[2] + bias1);
      const float y3 = sigmoid_f(d[3] + bias1);
      uint32_t* yd = (uint32_t*)&yw[l15 * 72 + ct * 16 + lg * 4];
      yd[0] = pk2bf(y0, y1);
      yd[1] = pk2bf(y2, y3);
    }
    {
      const uint16_t* yrow = &yw[l15 * 72 + lg * 8];
      bf16x8 ya0 = *(const bf16x8*)(yrow + 0);
      bf16x8 ya1 = *(const bf16x8*)(yrow + 32);
      if (cc == 0) {
        acc2 = __builtin_amdgcn_mfma_f32_16x16x32_bf16(ya0, w2f0, acc2, 0, 0, 0);
        acc2 = __builtin_amdgcn_mfma_f32_16x16x32_bf16(ya1, w2f1, acc2, 0, 0, 0);
      } else if (cc == 1) {
        acc2 = __builtin_amdgcn_mfma_f32_16x16x32_bf16(ya0, w2f2, acc2, 0, 0, 0);
        acc2 = __builtin_amdgcn_mfma_f32_16x16x32_bf16(ya1, w2f3, acc2, 0, 0, 0);
      } else if (cc == 2) {
        acc2 = __builtin_amdgcn_mfma_f32_16x16x32_bf16(ya0, w2f4, acc2, 0, 0, 0);
        acc2 = __builtin_amdgcn_mfma_f32_16x16x32_bf16(ya1, w2f5, acc2, 0, 0, 0);
      } else {
        acc2 = __builtin_amdgcn_mfma_f32_16x16x32_bf16(ya0, w2f6, acc2, 0, 0, 0);
        acc2 = __builtin_amdgcn_mfma_f32_16x16x32_bf16(ya1, w2f7, acc2, 0, 0, 0);
      }
    }
  }

  // epilogue: y2 = sigmoid(acc2 + b2) -> bf16 q/k/vT
  const int s   = l15;
  const int n   = (s & 1) * 2 + (r & 1);
  const int xsp = (s >> 1) * 8 + (r >> 1);
  const int bn  = b * 4 + n;
  uint16_t* qk = wsu + ((m == 0) ? QU_O : KU_O);
  uint16_t* vT = wsu + VT_O;
  #pragma unroll
  for (int p = 0; p < 4; ++p) {
    const int o = o_blk + lg * 4 + p;
    const uint16_t y2 = f2bf(sigmoid_f(acc2[p] + b2v));
    if (m == 2) vT[((size_t)bn * 64 + xsp) * 1024 + o] = y2;
    else        qk[((size_t)bn * 1024 + o) * 64 + xsp] = y2;
  }
}

// K3 (fused split-KV flash + in-block merge):
// grid 512 = 8 bn x 64 c-tiles, block 512 = 8 waves; wave w owns e-chunk
// [w*128, w*128+128) as 2 tiles of 64. After compute: barrier -> partials
// (O^T stride-68 rows + m,l) into LDS (aliases dead P buffers) -> barrier ->
// 512-thread max-rebase merge -> out. No k4, no global partials.
__global__ __launch_bounds__(512, 2) void k3_attn(
    const uint16_t* __restrict__ qu, const uint16_t* __restrict__ ku,
    const uint16_t* __restrict__ vtu, const float* __restrict__ temp,
    float* __restrict__ out) {
  const int tid = threadIdx.x;
  const int wv  = tid >> 6;
  const int l   = tid & 63;
  const int l15 = l & 15, lg = l >> 4;
  const int bn = blockIdx.x >> 6;
  const int ct = blockIdx.x & 63;
  const int cbase = ct * 16;
  const float tscale = temp[bn & 3];

  __shared__ __align__(16) char SH[36864];
  uint16_t* plw = (uint16_t*)SH + wv * 2304;   // per-wave P double-buffer (2x1152)
  float* poS = (float*)SH;                     // [8 waves][16 c][68] partial O^T
  float* mlS = poS + 8704;                     // [8 waves][32]: 16 m + 16 l

  // Q B-frags: B[k=d][col=c] from Q[bn][c][d]
  const uint16_t* qrow = qu + (size_t)(bn * 1024 + cbase + l15) * 64 + lg * 8;
  const bf16x8 qf0 = *(const bf16x8*)(qrow);
  const bf16x8 qf1 = *(const bf16x8*)(qrow + 32);

  const uint16_t* kb = ku  + (size_t)bn * 65536 + lg * 8;
  const uint16_t* vb = vtu + (size_t)bn * 65536 + lg * 8;

  f32x4 o0 = {0.f,0.f,0.f,0.f}, o1 = o0, o2 = o0, o3 = o0;  // O^T[x][c], 4 x-tiles
  float mrun = -3.0e38f, lrun = 0.f;

  #pragma unroll
  for (int et = 0; et < 2; ++et) {
    const int e0 = wv * 128 + et * 64;
    uint16_t* pl = plw + (et & 1) * 1152;

    // ---- S^T tile: D[e][c] = sum_d K[e][d] Q[c][d], 4 e-subtiles ----
    f32x4 s0 = {0.f,0.f,0.f,0.f}, s1 = s0, s2 = s0, s3 = s0;
    {
      const uint16_t* kr0 = kb + (size_t)(e0 +  0 + l15) * 64;
      const uint16_t* kr1 = kb + (size_t)(e0 + 16 + l15) * 64;
      const uint16_t* kr2 = kb + (size_t)(e0 + 32 + l15) * 64;
      const uint16_t* kr3 = kb + (size_t)(e0 + 48 + l15) * 64;
      const bf16x8 ka0 = *(const bf16x8*)(kr0);
      const bf16x8 kb0 = *(const bf16x8*)(kr0 + 32);
      const bf16x8 ka1 = *(const bf16x8*)(kr1);
      const bf16x8 kb1_ = *(const bf16x8*)(kr1 + 32);
      const bf16x8 ka2 = *(const bf16x8*)(kr2);
      const bf16x8 kb2_ = *(const bf16x8*)(kr2 + 32);
      const bf16x8 ka3 = *(const bf16x8*)(kr3);
      const bf16x8 kb3_ = *(const bf16x8*)(kr3 + 32);
      s0 = __builtin_amdgcn_mfma_f32_16x16x32_bf16(ka0, qf0, s0, 0,0,0);
      s0 = __builtin_amdgcn_mfma_f32_16x16x32_bf16(kb0, qf1, s0, 0,0,0);
      s1 = __builtin_amdgcn_mfma_f32_16x16x32_bf16(ka1, qf0, s1, 0,0,0);
      s1 = __builtin_amdgcn_mfma_f32_16x16x32_bf16(kb1_, qf1, s1, 0,0,0);
      s2 = __builtin_amdgcn_mfma_f32_16x16x32_bf16(ka2, qf0, s2, 0,0,0);
      s2 = __builtin_amdgcn_mfma_f32_16x16x32_bf16(kb2_, qf1, s2, 0,0,0);
      s3 = __builtin_amdgcn_mfma_f32_16x16x32_bf16(ka3, qf0, s3, 0,0,0);
      s3 = __builtin_amdgcn_mfma_f32_16x16x32_bf16(kb3_, qf1, s3, 0,0,0);
    }
    #pragma unroll
    for (int p = 0; p < 4; ++p) {
      s0[p] *= tscale; s1[p] *= tscale; s2[p] *= tscale; s3[p] *= tscale;
    }

    // ---- online softmax per c (col = l15) ----
    float t0 = fmaxf(fmaxf(s0[0], s0[1]), fmaxf(s0[2], s0[3]));
    float t1 = fmaxf(fmaxf(s1[0], s1[1]), fmaxf(s1[2], s1[3]));
    float t2 = fmaxf(fmaxf(s2[0], s2[1]), fmaxf(s2[2], s2[3]));
    float t3 = fmaxf(fmaxf(s3[0], s3[1]), fmaxf(s3[2], s3[3]));
    float tmax = fmaxf(fmaxf(t0, t1), fmaxf(t2, t3));
    tmax = fmaxf(tmax, __shfl_xor(tmax, 16, 64));
    tmax = fmaxf(tmax, __shfl_xor(tmax, 32, 64));
    const float mnew = fmaxf(mrun, tmax);
    const float scl  = __expf(mrun - mnew);
    float psum = 0.f;
    #pragma unroll
    for (int p = 0; p < 4; ++p) { s0[p] = __expf(s0[p] - mnew); psum += s0[p]; }
    #pragma unroll
    for (int p = 0; p < 4; ++p) { s1[p] = __expf(s1[p] - mnew); psum += s1[p]; }
    #pragma unroll
    for (int p = 0; p < 4; ++p) { s2[p] = __expf(s2[p] - mnew); psum += s2[p]; }
    #pragma unroll
    for (int p = 0; p < 4; ++p) { s3[p] = __expf(s3[p] - mnew); psum += s3[p]; }
    psum += __shfl_xor(psum, 16, 64);
    psum += __shfl_xor(psum, 32, 64);
    lrun = lrun * scl + psum;
    mrun = mnew;

    // ---- pack P -> LDS [c][e] ----
    {
      uint32_t* p0w = (uint32_t*)&pl[l15 * 72 +  0 + lg * 4];
      uint32_t* p1w = (uint32_t*)&pl[l15 * 72 + 16 + lg * 4];
      uint32_t* p2w = (uint32_t*)&pl[l15 * 72 + 32 + lg * 4];
      uint32_t* p3w = (uint32_t*)&pl[l15 * 72 + 48 + lg * 4];
      p0w[0] = pk2bf(s0[0], s0[1]); p0w[1] = pk2bf(s0[2], s0[3]);
      p1w[0] = pk2bf(s1[0], s1[1]); p1w[1] = pk2bf(s1[2], s1[3]);
      p2w[0] = pk2bf(s2[0], s2[1]); p2w[1] = pk2bf(s2[2], s2[3]);
      p3w[0] = pk2bf(s3[0], s3[1]); p3w[1] = pk2bf(s3[2], s3[3]);
    }

    // ---- rescale O^T by scl (per-c = lane-local) ----
    #pragma unroll
    for (int p = 0; p < 4; ++p) {
      o0[p] *= scl; o1[p] *= scl; o2[p] *= scl; o3[p] *= scl;
    }

    // ---- PV: O^T[x][c] += sum_e V^T[x][e] P[e][c] ----
    {
      const bf16x8 pb0 = *(const bf16x8*)&pl[l15 * 72 +  0 + lg * 8];
      const bf16x8 pb1 = *(const bf16x8*)&pl[l15 * 72 + 32 + lg * 8];
      const uint16_t* vr0 = vb + (size_t)( 0 + l15) * 1024 + e0;
      const uint16_t* vr1 = vb + (size_t)(16 + l15) * 1024 + e0;
      const uint16_t* vr2 = vb + (size_t)(32 + l15) * 1024 + e0;
      const uint16_t* vr3 = vb + (size_t)(48 + l15) * 1024 + e0;
      bf16x8 va;
      va = *(const bf16x8*)(vr0);      o0 = __builtin_amdgcn_mfma_f32_16x16x32_bf16(va, pb0, o0, 0,0,0);
      va = *(const bf16x8*)(vr0 + 32); o0 = __builtin_amdgcn_mfma_f32_16x16x32_bf16(va, pb1, o0, 0,0,0);
      va = *(const bf16x8*)(vr1);      o1 = __builtin_amdgcn_mfma_f32_16x16x32_bf16(va, pb0, o1, 0,0,0);
      va = *(const bf16x8*)(vr1 + 32); o1 = __builtin_amdgcn_mfma_f32_16x16x32_bf16(va, pb1, o1, 0,0,0);
      va = *(const bf16x8*)(vr2);      o2 = __builtin_amdgcn_mfma_f32_16x16x32_bf16(va, pb0, o2, 0,0,0);
      va = *(const bf16x8*)(vr2 + 32); o2 = __builtin_amdgcn_mfma_f32_16x16x32_bf16(va, pb1, o2, 0,0,0);
      va = *(const bf16x8*)(vr3);      o3 = __builtin_amdgcn_mfma_f32_16x16x32_bf16(va, pb0, o3, 0,0,0);
      va = *(const bf16x8*)(vr3 + 32); o3 = __builtin_amdgcn_mfma_f32_16x16x32_bf16(va, pb1, o3, 0,0,0);
    }
  }

  // ---- all waves done with their P buffers before aliasing them ----
  __syncthreads();

  // partial O^T -> poS[wv][c*68 + x]  (x = xt*16 + lg*4 + p), stride 68 = 2-way banks
  {
    float* po = poS + wv * 1088 + l15 * 68 + lg * 4;
    *(f32x4*)&po[ 0] = o0;
    *(f32x4*)&po[16] = o1;
    *(f32x4*)&po[32] = o2;
    *(f32x4*)&po[48] = o3;
    if (lg == 0) {
      mlS[wv * 32 + l15]      = mrun;
      mlS[wv * 32 + 16 + l15] = lrun;
    }
  }
  __syncthreads();

  // ---- merge: thread handles (c = tid>>5, x2 = (tid&31)*2, x2+1) ----
  {
    const int c  = tid >> 5;
    const int x2 = (tid & 31) * 2;

    float m0 = mlS[0 * 32 + c], m1 = mlS[1 * 32 + c];
    float m2 = mlS[2 * 32 + c], m3 = mlS[3 * 32 + c];
    float m4 = mlS[4 * 32 + c], m5 = mlS[5 * 32 + c];
    float m6 = mlS[6 * 32 + c], m7 = mlS[7 * 32 + c];
    const float M = fmaxf(fmaxf(fmaxf(m0, m1), fmaxf(m2, m3)),
                          fmaxf(fmaxf(m4, m5), fmaxf(m6, m7)));
    const float c0 = __expf(m0 - M), c1 = __expf(m1 - M);
    const float c2 = __expf(m2 - M), c3 = __expf(m3 - M);
    const float c4 = __expf(m4 - M), c5 = __expf(m5 - M);
    const float c6 = __expf(m6 - M), c7 = __expf(m7 - M);
    const float L = c0 * mlS[0 * 32 + 16 + c] + c1 * mlS[1 * 32 + 16 + c]
                  + c2 * mlS[2 * 32 + 16 + c] + c3 * mlS[3 * 32 + 16 + c]
                  + c4 * mlS[4 * 32 + 16 + c] + c5 * mlS[5 * 32 + 16 + c]
                  + c6 * mlS[6 * 32 + 16 + c] + c7 * mlS[7 * 32 + 16 + c];
    const float rl = __builtin_amdgcn_rcpf(L);

    const float* pb = poS + c * 68 + x2;
    float a0 = 0.f, a1 = 0.f;
    a0 += c0 * pb[0 * 1088]; a1 += c0 * pb[0 * 1088 + 1];
    a0 += c1 * pb[1 * 1088]; a1 += c1 * pb[1 * 1088 + 1];
    a0 += c2 * pb[2 * 1088]; a1 += c2 * pb[2 * 1088 + 1];
    a0 += c3 * pb[3 * 1088]; a1 += c3 * pb[3 * 1088 + 1];
    a0 += c4 * pb[4 * 1088]; a1 += c4 * pb[4 * 1088 + 1];
    a0 += c5 * pb[5 * 1088]; a1 += c5 * pb[5 * 1088 + 1];
    a0 += c6 * pb[6 * 1088]; a1 += c6 * pb[6 * 1088 + 1];
    a0 += c7 * pb[7 * 1088]; a1 += c7 * pb[7 * 1088 + 1];

    const int C = cbase + c;
    float* ob = out + ((size_t)bn * 256 + (C >> 2)) * 256 + (C & 3) * 64 + x2;
    ob[0] = a0 * rl;
    ob[1] = a1 * rl;
  }
}

extern "C" void kernel_launch(void* const* d_in, const int* in_sizes, int n_in,
                              void* d_out, int out_size, void* d_ws, size_t ws_size,
                              hipStream_t stream) {
  (void)in_sizes; (void)n_in; (void)out_size; (void)ws_size;
  const float* x      = (const float*)d_in[0];
  const float* conv_w = (const float*)d_in[1];
  const float* conv_b = (const float*)d_in[2];
  const float* qW1 = (const float*)d_in[3];
  const float* qb1 = (const float*)d_in[4];
  const float* qW2 = (const float*)d_in[5];
  const float* qb2 = (const float*)d_in[6];
  const float* kW1 = (const float*)d_in[7];
  const float* kb1 = (const float*)d_in[8];
  const float* kW2 = (const float*)d_in[9];
  const float* kb2 = (const float*)d_in[10];
  const float* vW1 = (const float*)d_in[11];
  const float* vb1 = (const float*)d_in[12];
  const float* vW2 = (const float*)d_in[13];
  const float* vb2 = (const float*)d_in[14];
  const float* temp = (const float*)d_in[15];
  float* wsf = (float*)d_ws;
  uint16_t* wsu = (uint16_t*)(wsf + U16_BASE_F);
  float* out = (float*)d_out;

  k1_G<<<dim3(1606), dim3(64), 0, stream>>>(x, qW1, kW1, vW1,
      conv_w, qW2, kW2, vW2, wsf, wsu);
  k2_mfma<<<dim3(1536), dim3(256), 0, stream>>>(
      wsu + GP_U, wsu + CW_U, wsu + W2T_U, conv_b,
      qb1, kb1, vb1, qb2, kb2, vb2, wsf, wsu);
  k3_attn<<<dim3(512), dim3(512), 0, stream>>>(
      wsu + QU_O, wsu + KU_O, wsu + VT_O, temp, out);
}

// Round 11
// 47.603 us; speedup vs baseline: 3.7720x; 1.0308x over previous
//
#include <hip/hip_runtime.h>
#include <cstdint>

constexpr int NB  = 2;     // batch
constexpr int NCI = 4;     // conv input channels
constexpr int NHH = 256;   // H
constexpr int NWW = 256;   // W
constexpr int NCT = 1024;  // conv output channels

// ---------------- workspace layout ----------------
constexpr size_t SW1F = 0;            // 48 floats
constexpr size_t U16_BASE_F = 48;     // u16 region starts here
// u16 offsets (relative to wsu):
constexpr size_t GP_U  = 0;           // G'bf [m][b][i][dx][r][258]
constexpr size_t CW_U  = 297216;      // CW_bf [o][40]
constexpr size_t W2T_U = 338176;      // W2T_bf [m][s][h]
constexpr size_t QU_O  = 350464;      // Q  bf16 [bn][o][xsp]
constexpr size_t KU_O  = 874752;      // K  bf16 [bn][o][xsp]
constexpr size_t VT_O  = 1399040;     // V^T bf16 [bn][xsp][o]

typedef __attribute__((ext_vector_type(8))) short bf16x8;
typedef __attribute__((ext_vector_type(4))) float f32x4;

__device__ __forceinline__ uint16_t f2bf(float x) {
  uint32_t u = __float_as_uint(x);
  return (uint16_t)((u + 0x7FFFu + ((u >> 16) & 1u)) >> 16);   // RNE
}
__device__ __forceinline__ uint32_t pk2bf(float a, float b) {  // lo=bf(a), hi=bf(b)
  const uint32_t au = __float_as_uint(a) + 0x8000u;
  const uint32_t bu = __float_as_uint(b) + 0x8000u;
  return __builtin_amdgcn_perm(bu, au, 0x07060302u);
}
__device__ __forceinline__ float sigmoid_f(float v) {
  return __builtin_amdgcn_rcpf(1.0f + __expf(-v));
}

// K1: G'bf[m][b][i][dx][r][1+h] = bf16( sum_w x_pad[b,i,h,w+dx-1] * W1_m[w,r] )
// plus sw1 sums, plus CW_bf / W2T_bf prep blocks.  (unchanged)
__global__ __launch_bounds__(64) void k1_G(
    const float* __restrict__ x,
    const float* __restrict__ qW1, const float* __restrict__ kW1,
    const float* __restrict__ vW1,
    const float* __restrict__ conv_w,
    const float* __restrict__ qW2, const float* __restrict__ kW2,
    const float* __restrict__ vW2,
    float* __restrict__ wsf, uint16_t* __restrict__ wsu) {
  const int tid = threadIdx.x;
  const int NBLK = 3 * NB * NCI * (NHH / 4);   // 1536
  int bid = blockIdx.x;

  if (bid >= NBLK + 3 + 64) {                  // W2T_bf prep (3 blocks)
    const int m = bid - (NBLK + 3 + 64);
    const float* W2 = (m == 0) ? qW2 : (m == 1) ? kW2 : vW2;
    for (int u = 0; u < 64; ++u) {
      const int idx = tid * 64 + u;            // 4096 = 16 s x 256 h
      const int s = idx >> 8, h = idx & 255;
      wsu[W2T_U + (size_t)m * 4096 + s * 256 + h] = f2bf(W2[h * 16 + s]);
    }
    return;
  }
  if (bid >= NBLK + 3) {                       // CW_bf prep (64 blocks x 16 o)
    const int p = bid - (NBLK + 3);
    const int o = p * 16 + (tid >> 2);
    const int ks = (tid & 3) * 10;
    for (int u = 0; u < 10; ++u) {
      const int k = ks + u;
      wsu[CW_U + (size_t)o * 40 + k] = (k < 36) ? f2bf(conv_w[o * 36 + k]) : (uint16_t)0;
    }
    return;
  }
  if (bid >= NBLK) {                           // sw1 column sums
    int m = bid - NBLK;
    if (tid < 16) {
      const float* W1 = (m == 0) ? qW1 : (m == 1) ? kW1 : vW1;
      float s = 0.f;
      for (int w = 0; w < 256; ++w) s += W1[w * 16 + tid];
      wsf[SW1F + m * 16 + tid] = s;
    }
    return;
  }

  const int m  = bid / (NB * NCI * (NHH / 4));
  int rem      = bid % (NB * NCI * (NHH / 4));
  const int b  = rem / (NCI * (NHH / 4));
  rem          = rem % (NCI * (NHH / 4));
  const int i  = rem / (NHH / 4);
  const int h0 = (rem % (NHH / 4)) * 4;
  const int mb = m * NB + b;

  const float* W1 = (m == 0) ? qW1 : (m == 1) ? kW1 : vW1;

  __shared__ float W1l[16 * 260];
  __shared__ float xlb[4][260];

  for (int idx4 = tid; idx4 < 1024; idx4 += 64) {
    const float4 t = ((const float4*)W1)[idx4];
    const int w = idx4 >> 2, r0 = (idx4 & 3) * 4;
    W1l[(r0 + 0) * 260 + w] = t.x;
    W1l[(r0 + 1) * 260 + w] = t.y;
    W1l[(r0 + 2) * 260 + w] = t.z;
    W1l[(r0 + 3) * 260 + w] = t.w;
  }
  const float* xbase = x + ((size_t)(b * NCI + i) * NHH + h0) * NWW;
  for (int idx = tid; idx < 4 * 256; idx += 64) {
    const int rr = idx >> 8, w = idx & 255;
    xlb[rr][1 + w] = xbase[rr * NWW + w];
  }
  if (tid < 4) {
    xlb[tid][0] = 0.f; xlb[tid][257] = 0.f; xlb[tid][258] = 0.f; xlb[tid][259] = 0.f;
  }
  __syncthreads();

  // pad rows hp=0 and hp=257 (zeros)
  if (h0 == 0 && tid < 48) {
    const int dxp = tid >> 4, rp = tid & 15;
    wsu[GP_U + ((size_t)((mb * 4 + i) * 3 + dxp) * 16 + rp) * 258 + 0] = 0;
  }
  if (h0 == 252 && tid < 48) {
    const int dxp = tid >> 4, rp = tid & 15;
    wsu[GP_U + ((size_t)((mb * 4 + i) * 3 + dxp) * 16 + rp) * 258 + 257] = 0;
  }

  const int wc = tid >> 4, r = tid & 15;
  const int w0 = wc * 64;
  const size_t gb0 = GP_U + ((size_t)((mb * 4 + i) * 3 + 0) * 16 + r) * 258;

  #pragma unroll
  for (int rr = 0; rr < 4; ++rr) {
    const float* xl = xlb[rr];
    float a0 = 0.f, a1 = 0.f, a2 = 0.f;
    float4 cur = *(const float4*)&xl[w0];
    #pragma unroll 4
    for (int w = w0; w < w0 + 64; w += 4) {
      const float4 nxt = *(const float4*)&xl[w + 4];
      const float4 w1  = *(const float4*)&W1l[r * 260 + w];
      a0 += w1.x * cur.x + w1.y * cur.y + w1.z * cur.z + w1.w * cur.w;
      a1 += w1.x * cur.y + w1.y * cur.z + w1.z * cur.w + w1.w * nxt.x;
      a2 += w1.x * cur.z + w1.y * cur.w + w1.z * nxt.x + w1.w * nxt.y;
      cur = nxt;
    }
    a0 += __shfl_xor(a0, 16, 64); a0 += __shfl_xor(a0, 32, 64);
    a1 += __shfl_xor(a1, 16, 64); a1 += __shfl_xor(a1, 32, 64);
    a2 += __shfl_xor(a2, 16, 64); a2 += __shfl_xor(a2, 32, 64);
    if (wc == 0) {
      const int hp = 1 + h0 + rr;
      wsu[gb0 + hp]        = f2bf(a0);   // dx = 0
      wsu[gb0 + 4128 + hp] = f2bf(a1);   // dx = 1
      wsu[gb0 + 8256 + hp] = f2bf(a2);   // dx = 2
    }
  }
}

// K2 (MFMA): bf16 epilogue: Q,K [bn][o][xsp], V^T [bn][xsp][o].  (unchanged)
__global__ __launch_bounds__(256, 4) void k2_mfma(
    const uint16_t* __restrict__ gp, const uint16_t* __restrict__ cwbf,
    const uint16_t* __restrict__ w2t,
    const float* __restrict__ conv_b,
    const float* __restrict__ qb1, const float* __restrict__ kb1, const float* __restrict__ vb1,
    const float* __restrict__ qb2, const float* __restrict__ kb2, const float* __restrict__ vb2,
    const float* __restrict__ wsf, uint16_t* __restrict__ wsu) {
  const int tid = threadIdx.x;
  const int bid = blockIdx.x;
  const int r  = bid & 15;
  const int og = (bid >> 4) & 15;
  const int mb = bid >> 8;            // 0..5
  const int m  = mb >> 1, b = mb & 1;

  const int wv  = tid >> 6;
  const int l   = tid & 63;
  const int l15 = l & 15;
  const int lg  = l >> 4;

  __shared__ uint16_t GS[256 * 40];     // [h][k]
  __shared__ uint16_t y1l[4][16 * 72];  // per-wave [o16][h64+8pad]

  {
    const int h = tid;
    uint16_t* gsrow = &GS[h * 40];
    #pragma unroll
    for (int i = 0; i < 4; ++i) {
      #pragma unroll
      for (int dx = 0; dx < 3; ++dx) {
        const uint16_t* g = gp + ((size_t)((mb * 4 + i) * 3 + dx) * 16 + r) * 258 + h;
        gsrow[i * 9 + 0 * 3 + dx] = g[0];
        gsrow[i * 9 + 1 * 3 + dx] = g[1];
        gsrow[i * 9 + 2 * 3 + dx] = g[2];
      }
    }
    gsrow[36] = 0; gsrow[37] = 0; gsrow[38] = 0; gsrow[39] = 0;
  }
  __syncthreads();

  const float* b1 = (m == 0) ? qb1 : (m == 1) ? kb1 : vb1;
  const float* b2 = (m == 0) ? qb2 : (m == 1) ? kb2 : vb2;

  const int o_blk = og * 64 + wv * 16;

  const uint16_t* cwrow = cwbf + (size_t)(o_blk + l15) * 40;
  bf16x8 cw0 = *(const bf16x8*)(cwrow + lg * 8);
  bf16x8 cw1 = {0,0,0,0,0,0,0,0};
  if (lg == 0) cw1 = *(const bf16x8*)(cwrow + 32);

  const uint16_t* w2row = w2t + (size_t)m * 4096 + (size_t)l15 * 256 + lg * 8;
  bf16x8 w2f0 = *(const bf16x8*)(w2row + 0 * 32);
  bf16x8 w2f1 = *(const bf16x8*)(w2row + 1 * 32);
  bf16x8 w2f2 = *(const bf16x8*)(w2row + 2 * 32);
  bf16x8 w2f3 = *(const bf16x8*)(w2row + 3 * 32);
  bf16x8 w2f4 = *(const bf16x8*)(w2row + 4 * 32);
  bf16x8 w2f5 = *(const bf16x8*)(w2row + 5 * 32);
  bf16x8 w2f6 = *(const bf16x8*)(w2row + 6 * 32);
  bf16x8 w2f7 = *(const bf16x8*)(w2row + 7 * 32);

  const float sw1r = wsf[SW1F + m * 16 + r];
  const float b1r  = b1[r];
  const float cbv  = conv_b[o_blk + l15];
  const float bias1 = cbv * sw1r + b1r;
  const float b2v  = b2[l15];

  uint16_t* yw = &y1l[wv][0];
  f32x4 acc2 = {0.f, 0.f, 0.f, 0.f};

  #pragma unroll
  for (int cc = 0; cc < 4; ++cc) {
    #pragma unroll
    for (int ct = 0; ct < 4; ++ct) {
      const uint16_t* arow = &GS[(cc * 64 + ct * 16 + l15) * 40];
      bf16x8 a0 = *(const bf16x8*)(arow + lg * 8);
      bf16x8 a1 = {0,0,0,0,0,0,0,0};
      if (lg == 0) a1 = *(const bf16x8*)(arow + 32);
      f32x4 d = {0.f, 0.f, 0.f, 0.f};
      d = __builtin_amdgcn_mfma_f32_16x16x32_bf16(a0, cw0, d, 0, 0, 0);
      d = __builtin_amdgcn_mfma_f32_16x16x32_bf16(a1, cw1, d, 0, 0, 0);
      const float y0 = sigmoid_f(d[0] + bias1);
      const float y1 = sigmoid_f(d[1] + bias1);
      const float y2 = sigmoid_f(d[2] + bias1);
      const float y3 = sigmoid_f(d[3] + bias1);
      uint32_t* yd = (uint32_t*)&yw[l15 * 72 + ct * 16 + lg * 4];
      yd[0] = pk2bf(y0, y1);
      yd[1] = pk2bf(y2, y3);
    }
    {
      const uint16_t* yrow = &yw[l15 * 72 + lg * 8];
      bf16x8 ya0 = *(const bf16x8*)(yrow + 0);
      bf16x8 ya1 = *(const bf16x8*)(yrow + 32);
      if (cc == 0) {
        acc2 = __builtin_amdgcn_mfma_f32_16x16x32_bf16(ya0, w2f0, acc2, 0, 0, 0);
        acc2 = __builtin_amdgcn_mfma_f32_16x16x32_bf16(ya1, w2f1, acc2, 0, 0, 0);
      } else if (cc == 1) {
        acc2 = __builtin_amdgcn_mfma_f32_16x16x32_bf16(ya0, w2f2, acc2, 0, 0, 0);
        acc2 = __builtin_amdgcn_mfma_f32_16x16x32_bf16(ya1, w2f3, acc2, 0, 0, 0);
      } else if (cc == 2) {
        acc2 = __builtin_amdgcn_mfma_f32_16x16x32_bf16(ya0, w2f4, acc2, 0, 0, 0);
        acc2 = __builtin_amdgcn_mfma_f32_16x16x32_bf16(ya1, w2f5, acc2, 0, 0, 0);
      } else {
        acc2 = __builtin_amdgcn_mfma_f32_16x16x32_bf16(ya0, w2f6, acc2, 0, 0, 0);
        acc2 = __builtin_amdgcn_mfma_f32_16x16x32_bf16(ya1, w2f7, acc2, 0, 0, 0);
      }
    }
  }

  // epilogue: y2 = sigmoid(acc2 + b2) -> bf16 q/k/vT
  const int s   = l15;
  const int n   = (s & 1) * 2 + (r & 1);
  const int xsp = (s >> 1) * 8 + (r >> 1);
  const int bn  = b * 4 + n;
  uint16_t* qk = wsu + ((m == 0) ? QU_O : KU_O);
  uint16_t* vT = wsu + VT_O;
  #pragma unroll
  for (int p = 0; p < 4; ++p) {
    const int o = o_blk + lg * 4 + p;
    const uint16_t y2 = f2bf(sigmoid_f(acc2[p] + b2v));
    if (m == 2) vT[((size_t)bn * 64 + xsp) * 1024 + o] = y2;
    else        qk[((size_t)bn * 1024 + o) * 64 + xsp] = y2;
  }
}

// K3 (fused flash + in-block merge, XCD-pinned, batched prologue loads):
// grid 512; bn = bid&7 (dispatch round-robins XCDs by bid%8 -> all blocks of a
// bn share one XCD's L2; K/V working set 256 KB stays local). block 512 = 8
// waves; wave w owns e in [w*128, w*128+128) as 2 straight-line 64-tiles with
// K0/K1/V0 issued up front and V1 right after QK0 (one far-memory latency).
__global__ __launch_bounds__(512, 2) void k3_attn(
    const uint16_t* __restrict__ qu, const uint16_t* __restrict__ ku,
    const uint16_t* __restrict__ vtu, const float* __restrict__ temp,
    float* __restrict__ out) {
  const int tid = threadIdx.x;
  const int wv  = tid >> 6;
  const int l   = tid & 63;
  const int l15 = l & 15, lg = l >> 4;
  const int bid = blockIdx.x;
  const int bn = bid & 7;          // XCD pin
  const int ct = bid >> 3;
  const int cbase = ct * 16;
  const float tscale = temp[bn & 3];

  __shared__ __align__(16) char SH[36864];
  uint16_t* pl  = (uint16_t*)SH + wv * 2304;   // per-wave P buffer (single, 1152 used)
  float* poS = (float*)SH;                     // [8 waves][16 c][68] partial O^T
  float* mlS = poS + 8704;                     // [8 waves][32]: 16 m + 16 l

  // ---- prologue: Q frags + K0 + K1 + V0 ----
  const uint16_t* qrow = qu + (size_t)(bn * 1024 + cbase + l15) * 64 + lg * 8;
  const bf16x8 qf0 = *(const bf16x8*)(qrow);
  const bf16x8 qf1 = *(const bf16x8*)(qrow + 32);

  const uint16_t* kb = ku  + (size_t)bn * 65536 + lg * 8;
  const uint16_t* vb = vtu + (size_t)bn * 65536 + lg * 8;
  const int e0a = wv * 128, e0b = e0a + 64;

  const uint16_t* ka_r0 = kb + (size_t)(e0a +  0 + l15) * 64;
  const uint16_t* ka_r1 = kb + (size_t)(e0a + 16 + l15) * 64;
  const uint16_t* ka_r2 = kb + (size_t)(e0a + 32 + l15) * 64;
  const uint16_t* ka_r3 = kb + (size_t)(e0a + 48 + l15) * 64;
  const bf16x8 k0a = *(const bf16x8*)(ka_r0);
  const bf16x8 k0b = *(const bf16x8*)(ka_r0 + 32);
  const bf16x8 k1a = *(const bf16x8*)(ka_r1);
  const bf16x8 k1b = *(const bf16x8*)(ka_r1 + 32);
  const bf16x8 k2a = *(const bf16x8*)(ka_r2);
  const bf16x8 k2b = *(const bf16x8*)(ka_r2 + 32);
  const bf16x8 k3a = *(const bf16x8*)(ka_r3);
  const bf16x8 k3b = *(const bf16x8*)(ka_r3 + 32);

  const uint16_t* kb_r0 = kb + (size_t)(e0b +  0 + l15) * 64;
  const uint16_t* kb_r1 = kb + (size_t)(e0b + 16 + l15) * 64;
  const uint16_t* kb_r2 = kb + (size_t)(e0b + 32 + l15) * 64;
  const uint16_t* kb_r3 = kb + (size_t)(e0b + 48 + l15) * 64;
  const bf16x8 k4a = *(const bf16x8*)(kb_r0);
  const bf16x8 k4b = *(const bf16x8*)(kb_r0 + 32);
  const bf16x8 k5a = *(const bf16x8*)(kb_r1);
  const bf16x8 k5b = *(const bf16x8*)(kb_r1 + 32);
  const bf16x8 k6a = *(const bf16x8*)(kb_r2);
  const bf16x8 k6b = *(const bf16x8*)(kb_r2 + 32);
  const bf16x8 k7a = *(const bf16x8*)(kb_r3);
  const bf16x8 k7b = *(const bf16x8*)(kb_r3 + 32);

  const uint16_t* vr0 = vb + (size_t)( 0 + l15) * 1024;
  const uint16_t* vr1 = vb + (size_t)(16 + l15) * 1024;
  const uint16_t* vr2 = vb + (size_t)(32 + l15) * 1024;
  const uint16_t* vr3 = vb + (size_t)(48 + l15) * 1024;
  const bf16x8 v0a = *(const bf16x8*)(vr0 + e0a);
  const bf16x8 v0b = *(const bf16x8*)(vr0 + e0a + 32);
  const bf16x8 v1a = *(const bf16x8*)(vr1 + e0a);
  const bf16x8 v1b = *(const bf16x8*)(vr1 + e0a + 32);
  const bf16x8 v2a = *(const bf16x8*)(vr2 + e0a);
  const bf16x8 v2b = *(const bf16x8*)(vr2 + e0a + 32);
  const bf16x8 v3a = *(const bf16x8*)(vr3 + e0a);
  const bf16x8 v3b = *(const bf16x8*)(vr3 + e0a + 32);

  f32x4 o0 = {0.f,0.f,0.f,0.f}, o1 = o0, o2 = o0, o3 = o0;
  float mrun, lrun;

  // ================= tile 0 =================
  f32x4 s0 = {0.f,0.f,0.f,0.f}, s1 = s0, s2 = s0, s3 = s0;
  s0 = __builtin_amdgcn_mfma_f32_16x16x32_bf16(k0a, qf0, s0, 0,0,0);
  s0 = __builtin_amdgcn_mfma_f32_16x16x32_bf16(k0b, qf1, s0, 0,0,0);
  s1 = __builtin_amdgcn_mfma_f32_16x16x32_bf16(k1a, qf0, s1, 0,0,0);
  s1 = __builtin_amdgcn_mfma_f32_16x16x32_bf16(k1b, qf1, s1, 0,0,0);
  s2 = __builtin_amdgcn_mfma_f32_16x16x32_bf16(k2a, qf0, s2, 0,0,0);
  s2 = __builtin_amdgcn_mfma_f32_16x16x32_bf16(k2b, qf1, s2, 0,0,0);
  s3 = __builtin_amdgcn_mfma_f32_16x16x32_bf16(k3a, qf0, s3, 0,0,0);
  s3 = __builtin_amdgcn_mfma_f32_16x16x32_bf16(k3b, qf1, s3, 0,0,0);

  // issue V1 loads now (latency hides under softmax0/PV0/QK1/softmax1)
  const bf16x8 w0a = *(const bf16x8*)(vr0 + e0b);
  const bf16x8 w0b = *(const bf16x8*)(vr0 + e0b + 32);
  const bf16x8 w1a = *(const bf16x8*)(vr1 + e0b);
  const bf16x8 w1b = *(const bf16x8*)(vr1 + e0b + 32);
  const bf16x8 w2a = *(const bf16x8*)(vr2 + e0b);
  const bf16x8 w2b = *(const bf16x8*)(vr2 + e0b + 32);
  const bf16x8 w3a = *(const bf16x8*)(vr3 + e0b);
  const bf16x8 w3b = *(const bf16x8*)(vr3 + e0b + 32);

  {
    #pragma unroll
    for (int p = 0; p < 4; ++p) {
      s0[p] *= tscale; s1[p] *= tscale; s2[p] *= tscale; s3[p] *= tscale;
    }
    float t0 = fmaxf(fmaxf(s0[0], s0[1]), fmaxf(s0[2], s0[3]));
    float t1 = fmaxf(fmaxf(s1[0], s1[1]), fmaxf(s1[2], s1[3]));
    float t2 = fmaxf(fmaxf(s2[0], s2[1]), fmaxf(s2[2], s2[3]));
    float t3 = fmaxf(fmaxf(s3[0], s3[1]), fmaxf(s3[2], s3[3]));
    float tmax = fmaxf(fmaxf(t0, t1), fmaxf(t2, t3));
    tmax = fmaxf(tmax, __shfl_xor(tmax, 16, 64));
    tmax = fmaxf(tmax, __shfl_xor(tmax, 32, 64));
    const float mnew = tmax;                     // mrun = -inf initially
    float psum = 0.f;
    #pragma unroll
    for (int p = 0; p < 4; ++p) { s0[p] = __expf(s0[p] - mnew); psum += s0[p]; }
    #pragma unroll
    for (int p = 0; p < 4; ++p) { s1[p] = __expf(s1[p] - mnew); psum += s1[p]; }
    #pragma unroll
    for (int p = 0; p < 4; ++p) { s2[p] = __expf(s2[p] - mnew); psum += s2[p]; }
    #pragma unroll
    for (int p = 0; p < 4; ++p) { s3[p] = __expf(s3[p] - mnew); psum += s3[p]; }
    psum += __shfl_xor(psum, 16, 64);
    psum += __shfl_xor(psum, 32, 64);
    lrun = psum;
    mrun = mnew;

    uint32_t* p0w = (uint32_t*)&pl[l15 * 72 +  0 + lg * 4];
    uint32_t* p1w = (uint32_t*)&pl[l15 * 72 + 16 + lg * 4];
    uint32_t* p2w = (uint32_t*)&pl[l15 * 72 + 32 + lg * 4];
    uint32_t* p3w = (uint32_t*)&pl[l15 * 72 + 48 + lg * 4];
    p0w[0] = pk2bf(s0[0], s0[1]); p0w[1] = pk2bf(s0[2], s0[3]);
    p1w[0] = pk2bf(s1[0], s1[1]); p1w[1] = pk2bf(s1[2], s1[3]);
    p2w[0] = pk2bf(s2[0], s2[1]); p2w[1] = pk2bf(s2[2], s2[3]);
    p3w[0] = pk2bf(s3[0], s3[1]); p3w[1] = pk2bf(s3[2], s3[3]);

    const bf16x8 pb0 = *(const bf16x8*)&pl[l15 * 72 +  0 + lg * 8];
    const bf16x8 pb1 = *(const bf16x8*)&pl[l15 * 72 + 32 + lg * 8];
    o0 = __builtin_amdgcn_mfma_f32_16x16x32_bf16(v0a, pb0, o0, 0,0,0);
    o0 = __builtin_amdgcn_mfma_f32_16x16x32_bf16(v0b, pb1, o0, 0,0,0);
    o1 = __builtin_amdgcn_mfma_f32_16x16x32_bf16(v1a, pb0, o1, 0,0,0);
    o1 = __builtin_amdgcn_mfma_f32_16x16x32_bf16(v1b, pb1, o1, 0,0,0);
    o2 = __builtin_amdgcn_mfma_f32_16x16x32_bf16(v2a, pb0, o2, 0,0,0);
    o2 = __builtin_amdgcn_mfma_f32_16x16x32_bf16(v2b, pb1, o2, 0,0,0);
    o3 = __builtin_amdgcn_mfma_f32_16x16x32_bf16(v3a, pb0, o3, 0,0,0);
    o3 = __builtin_amdgcn_mfma_f32_16x16x32_bf16(v3b, pb1, o3, 0,0,0);
  }

  // ================= tile 1 =================
  {
    f32x4 u0 = {0.f,0.f,0.f,0.f}, u1 = u0, u2 = u0, u3 = u0;
    u0 = __builtin_amdgcn_mfma_f32_16x16x32_bf16(k4a, qf0, u0, 0,0,0);
    u0 = __builtin_amdgcn_mfma_f32_16x16x32_bf16(k4b, qf1, u0, 0,0,0);
    u1 = __builtin_amdgcn_mfma_f32_16x16x32_bf16(k5a, qf0, u1, 0,0,0);
    u1 = __builtin_amdgcn_mfma_f32_16x16x32_bf16(k5b, qf1, u1, 0,0,0);
    u2 = __builtin_amdgcn_mfma_f32_16x16x32_bf16(k6a, qf0, u2, 0,0,0);
    u2 = __builtin_amdgcn_mfma_f32_16x16x32_bf16(k6b, qf1, u2, 0,0,0);
    u3 = __builtin_amdgcn_mfma_f32_16x16x32_bf16(k7a, qf0, u3, 0,0,0);
    u3 = __builtin_amdgcn_mfma_f32_16x16x32_bf16(k7b, qf1, u3, 0,0,0);

    #pragma unroll
    for (int p = 0; p < 4; ++p) {
      u0[p] *= tscale; u1[p] *= tscale; u2[p] *= tscale; u3[p] *= tscale;
    }
    float t0 = fmaxf(fmaxf(u0[0], u0[1]), fmaxf(u0[2], u0[3]));
    float t1 = fmaxf(fmaxf(u1[0], u1[1]), fmaxf(u1[2], u1[3]));
    float t2 = fmaxf(fmaxf(u2[0], u2[1]), fmaxf(u2[2], u2[3]));
    float t3 = fmaxf(fmaxf(u3[0], u3[1]), fmaxf(u3[2], u3[3]));
    float tmax = fmaxf(fmaxf(t0, t1), fmaxf(t2, t3));
    tmax = fmaxf(tmax, __shfl_xor(tmax, 16, 64));
    tmax = fmaxf(tmax, __shfl_xor(tmax, 32, 64));
    const float mnew = fmaxf(mrun, tmax);
    const float scl  = __expf(mrun - mnew);
    float psum = 0.f;
    #pragma unroll
    for (int p = 0; p < 4; ++p) { u0[p] = __expf(u0[p] - mnew); psum += u0[p]; }
    #pragma unroll
    for (int p = 0; p < 4; ++p) { u1[p] = __expf(u1[p] - mnew); psum += u1[p]; }
    #pragma unroll
    for (int p = 0; p < 4; ++p) { u2[p] = __expf(u2[p] - mnew); psum += u2[p]; }
    #pragma unroll
    for (int p = 0; p < 4; ++p) { u3[p] = __expf(u3[p] - mnew); psum += u3[p]; }
    psum += __shfl_xor(psum, 16, 64);
    psum += __shfl_xor(psum, 32, 64);
    lrun = lrun * scl + psum;
    mrun = mnew;

    uint32_t* p0w = (uint32_t*)&pl[l15 * 72 +  0 + lg * 4];
    uint32_t* p1w = (uint32_t*)&pl[l15 * 72 + 16 + lg * 4];
    uint32_t* p2w = (uint32_t*)&pl[l15 * 72 + 32 + lg * 4];
    uint32_t* p3w = (uint32_t*)&pl[l15 * 72 + 48 + lg * 4];
    p0w[0] = pk2bf(u0[0], u0[1]); p0w[1] = pk2bf(u0[2], u0[3]);
    p1w[0] = pk2bf(u1[0], u1[1]); p1w[1] = pk2bf(u1[2], u1[3]);
    p2w[0] = pk2bf(u2[0], u2[1]); p2w[1] = pk2bf(u2[2], u2[3]);
    p3w[0] = pk2bf(u3[0], u3[1]); p3w[1] = pk2bf(u3[2], u3[3]);

    #pragma unroll
    for (int p = 0; p < 4; ++p) {
      o0[p] *= scl; o1[p] *= scl; o2[p] *= scl; o3[p] *= scl;
    }

    const bf16x8 pb0 = *(const bf16x8*)&pl[l15 * 72 +  0 + lg * 8];
    const bf16x8 pb1 = *(const bf16x8*)&pl[l15 * 72 + 32 + lg * 8];
    o0 = __builtin_amdgcn_mfma_f32_16x16x32_bf16(w0a, pb0, o0, 0,0,0);
    o0 = __builtin_amdgcn_mfma_f32_16x16x32_bf16(w0b, pb1, o0, 0,0,0);
    o1 = __builtin_amdgcn_mfma_f32_16x16x32_bf16(w1a, pb0, o1, 0,0,0);
    o1 = __builtin_amdgcn_mfma_f32_16x16x32_bf16(w1b, pb1, o1, 0,0,0);
    o2 = __builtin_amdgcn_mfma_f32_16x16x32_bf16(w2a, pb0, o2, 0,0,0);
    o2 = __builtin_amdgcn_mfma_f32_16x16x32_bf16(w2b, pb1, o2, 0,0,0);
    o3 = __builtin_amdgcn_mfma_f32_16x16x32_bf16(w3a, pb0, o3, 0,0,0);
    o3 = __builtin_amdgcn_mfma_f32_16x16x32_bf16(w3b, pb1, o3, 0,0,0);
  }

  // ---- all waves done with P buffers before aliasing them ----
  __syncthreads();

  {
    float* po = poS + wv * 1088 + l15 * 68 + lg * 4;
    *(f32x4*)&po[ 0] = o0;
    *(f32x4*)&po[16] = o1;
    *(f32x4*)&po[32] = o2;
    *(f32x4*)&po[48] = o3;
    if (lg == 0) {
      mlS[wv * 32 + l15]      = mrun;
      mlS[wv * 32 + 16 + l15] = lrun;
    }
  }
  __syncthreads();

  // ---- merge: thread handles (c = tid>>5, x2 = (tid&31)*2, x2+1) ----
  {
    const int c  = tid >> 5;
    const int x2 = (tid & 31) * 2;

    float m0 = mlS[0 * 32 + c], m1 = mlS[1 * 32 + c];
    float m2 = mlS[2 * 32 + c], m3 = mlS[3 * 32 + c];
    float m4 = mlS[4 * 32 + c], m5 = mlS[5 * 32 + c];
    float m6 = mlS[6 * 32 + c], m7 = mlS[7 * 32 + c];
    const float M = fmaxf(fmaxf(fmaxf(m0, m1), fmaxf(m2, m3)),
                          fmaxf(fmaxf(m4, m5), fmaxf(m6, m7)));
    const float c0 = __expf(m0 - M), c1 = __expf(m1 - M);
    const float c2 = __expf(m2 - M), c3 = __expf(m3 - M);
    const float c4 = __expf(m4 - M), c5 = __expf(m5 - M);
    const float c6 = __expf(m6 - M), c7 = __expf(m7 - M);
    const float L = c0 * mlS[0 * 32 + 16 + c] + c1 * mlS[1 * 32 + 16 + c]
                  + c2 * mlS[2 * 32 + 16 + c] + c3 * mlS[3 * 32 + 16 + c]
                  + c4 * mlS[4 * 32 + 16 + c] + c5 * mlS[5 * 32 + 16 + c]
                  + c6 * mlS[6 * 32 + 16 + c] + c7 * mlS[7 * 32 + 16 + c];
    const float rl = __builtin_amdgcn_rcpf(L);

    const float* pb = poS + c * 68 + x2;
    float a0 = 0.f, a1 = 0.f;
    a0 += c0 * pb[0 * 1088]; a1 += c0 * pb[0 * 1088 + 1];
    a0 += c1 * pb[1 * 1088]; a1 += c1 * pb[1 * 1088 + 1];
    a0 += c2 * pb[2 * 1088]; a1 += c2 * pb[2 * 1088 + 1];
    a0 += c3 * pb[3 * 1088]; a1 += c3 * pb[3 * 1088 + 1];
    a0 += c4 * pb[4 * 1088]; a1 += c4 * pb[4 * 1088 + 1];
    a0 += c5 * pb[5 * 1088]; a1 += c5 * pb[5 * 1088 + 1];
    a0 += c6 * pb[6 * 1088]; a1 += c6 * pb[6 * 1088 + 1];
    a0 += c7 * pb[7 * 1088]; a1 += c7 * pb[7 * 1088 + 1];

    const int C = cbase + c;
    float* ob = out + ((size_t)bn * 256 + (C >> 2)) * 256 + (C & 3) * 64 + x2;
    ob[0] = a0 * rl;
    ob[1] = a1 * rl;
  }
}

extern "C" void kernel_launch(void* const* d_in, const int* in_sizes, int n_in,
                              void* d_out, int out_size, void* d_ws, size_t ws_size,
                              hipStream_t stream) {
  (void)in_sizes; (void)n_in; (void)out_size; (void)ws_size;
  const float* x      = (const float*)d_in[0];
  const float* conv_w = (const float*)d_in[1];
  const float* conv_b = (const float*)d_in[2];
  const float* qW1 = (const float*)d_in[3];
  const float* qb1 = (const float*)d_in[4];
  const float* qW2 = (const float*)d_in[5];
  const float* qb2 = (const float*)d_in[6];
  const float* kW1 = (const float*)d_in[7];
  const float* kb1 = (const float*)d_in[8];
  const float* kW2 = (const float*)d_in[9];
  const float* kb2 = (const float*)d_in[10];
  const float* vW1 = (const float*)d_in[11];
  const float* vb1 = (const float*)d_in[12];
  const float* vW2 = (const float*)d_in[13];
  const float* vb2 = (const float*)d_in[14];
  const float* temp = (const float*)d_in[15];
  float* wsf = (float*)d_ws;
  uint16_t* wsu = (uint16_t*)(wsf + U16_BASE_F);
  float* out = (float*)d_out;

  k1_G<<<dim3(1606), dim3(64), 0, stream>>>(x, qW1, kW1, vW1,
      conv_w, qW2, kW2, vW2, wsf, wsu);
  k2_mfma<<<dim3(1536), dim3(256), 0, stream>>>(
      wsu + GP_U, wsu + CW_U, wsu + W2T_U, conv_b,
      qb1, kb1, vb1, qb2, kb2, vb2, wsf, wsu);
  k3_attn<<<dim3(512), dim3(512), 0, stream>>>(
      wsu + QU_O, wsu + KU_O, wsu + VT_O, temp, out);
}